// Round 20
// baseline (508.539 us; speedup 1.0000x reference)
//
#include <hip/hip_runtime.h>
#include <hip/hip_bf16.h>
#include <math.h>

#define IHW 224
#define DIN 16
#define DOUT 8
#define HO 112
#define PO 56
// padded input geometry: pid = 2dd+kd in [0,21), pih = 2ho+kh in [0,229)<232, piw in [0,240)
#define DP 21
#define HP 232
#define WP 240
#define PLANE (HP * WP)   // 55680

typedef __bf16 bf16x8 __attribute__((ext_vector_type(8)));
typedef float f32x4 __attribute__((ext_vector_type(4)));
typedef float f32x16 __attribute__((ext_vector_type(16)));
typedef ushort u16x8 __attribute__((ext_vector_type(8)));

__device__ __forceinline__ ushort f2bf(float f) {
  uint u = __float_as_uint(f);
  uint r = (u + 0x7FFFu + ((u >> 16) & 1u)) >> 16;
  return (ushort)r;
}
__device__ __forceinline__ float bf2f(ushort u) {
  return __uint_as_float(((uint)u) << 16);
}

// ---------------- f32 [bc][16][224][224] -> padded bf16 [bc][21][232][240] (zeros in pads) ----------------
__global__ void cvt_pad(const float* __restrict__ in, ushort* __restrict__ out, int nbc) {
  const int v = blockIdx.x * 256 + threadIdx.x;         // ushort2 units
  const int total = nbc * DP * HP * (WP / 2);
  if (v >= total) return;
  const int pw2 = v % (WP / 2);
  int rest = v / (WP / 2);
  const int pih = rest % HP; rest /= HP;
  const int pid = rest % DP;
  const int bc = rest / DP;
  const int id = pid - 2, ih = pih - 2;
  ushort2 o = make_ushort2(0, 0);
  if (id >= 0 && id < DIN && ih >= 0 && ih < IHW) {
    const float* src = in + ((size_t)(bc * DIN + id) * IHW + ih) * IHW;
    const int iw0 = pw2 * 2 - 2;
    if (iw0 >= 0 && iw0 < IHW) o.x = f2bf(src[iw0]);
    if (iw0 + 1 >= 0 && iw0 + 1 < IHW) o.y = f2bf(src[iw0 + 1]);
  }
  reinterpret_cast<ushort2*>(out)[v] = o;
}

// ---------------- masking + pad: out[head*6 + b*3 + c][pid][pih][piw] bf16 ----------------
__global__ void masking_pad(const float* __restrict__ rgbs, const float* __restrict__ mask,
                            const float* __restrict__ bg, ushort* __restrict__ out) {
  const int v = blockIdx.x * 256 + threadIdx.x;         // ushort2 units
  const int total = 12 * DP * HP * (WP / 2);
  if (v >= total) return;
  const int pw2 = v % (WP / 2);
  int rest = v / (WP / 2);
  const int pih = rest % HP; rest /= HP;
  const int pid = rest % DP;
  const int bc = rest / DP;
  const int head = bc / 6;
  const int r6 = bc - head * 6;
  const int b = r6 / 3, c = r6 - (r6 / 3) * 3;
  const int t = pid - 2, ih = pih - 2;
  ushort2 o = make_ushort2(0, 0);
  if (t >= 0 && t < DIN && ih >= 0 && ih < IHW) {
    const float* mrow = mask + ((size_t)(b * DIN + t)) * (IHW * IHW) + ih * IHW;
    const float* rrow = rgbs + ((size_t)((b * 3 + c) * DIN + t)) * (IHW * IHW) + ih * IHW;
    const float* brow = bg + (size_t)c * (IHW * IHW) + ih * IHW;
    const int iw0 = pw2 * 2 - 2;
#pragma unroll
    for (int j = 0; j < 2; j++) {
      const int iw = iw0 + j;
      if (iw >= 0 && iw < IHW) {
        float m = mrow[iw];
        if (head) m = 1.f - m;
        const float val = rrow[iw] * m + brow[iw] * (1.f - m);
        if (j == 0) o.x = f2bf(val); else o.y = f2bf(val);
      }
    }
  }
  reinterpret_cast<ushort2*>(out)[v] = o;
}

// ---------------- weight prep: f32 [64][C][7][7][7] -> bf16 [oc][kw][KPAD] ----------------
// k = kd*(C*7) + c*7 + kh  (zeros for k >= C*49)
template<int C>
__global__ __launch_bounds__(256) void wprep(const float* __restrict__ w, ushort* __restrict__ wB) {
  constexpr int C7 = C * 7, KREAL = C * 49, KPAD = (C == 3) ? 160 : 128;
  const int idx = blockIdx.x * 256 + threadIdx.x;
  if (idx >= 64 * 7 * KPAD) return;
  const int k = idx % KPAD;
  const int rest = idx / KPAD;
  const int kw = rest % 7;
  const int oc = rest / 7;
  float val = 0.f;
  if (k < KREAL) {
    const int kd = k / C7, rem = k % C7, c = rem / 7, kh = rem % 7;
    val = w[(((oc * C + c) * 7 + kd) * 7 + kh) * 7 + kw];
  }
  wB[idx] = f2bf(val);
}

// ---------------- conv3d 7x7x7 s2 SAME + ReLU via bf16 MFMA 32x32x16 ----------------
// block x XCD-swizzled: hx = (bx%8)*28 + bx/8. 512 thr = 8 waves = 2 nh x 4 kseg
// (kw {0,1},{2,3},{4,5},{6}). Each wave does both mt tiles over its kw range ->
// B-frags loaded once per block; shorter per-wave chains + 2x wave count for latency.
// Cross-wave reduce: 2 rounds via conflict-free [w][r][lane] buffers (32KB <= LDS).
template<int C>
__global__ __launch_bounds__(512, 4) void conv_mfma(
    const ushort* __restrict__ in, const ushort* __restrict__ wB,
    ushort* __restrict__ out)
{
  constexpr int C7 = C * 7, KREAL = C * 49;
  constexpr int KPAD = (C == 3) ? 160 : 128;
  constexpr int NKS = KPAD / 16;         // 10 / 8
  constexpr int ROWB = KPAD * 2;
  constexpr int KG = KPAD / 4;
  constexpr int SROWS = 118;
  constexpr int NU2 = KG * 64 / 512;     // pair-units/thread: 5 / 4

  __shared__ char smem[SROWS * ROWB];    // 37,760B / 30,208B (staging; reduce bufs; eLDS)
  __shared__ int offt[KPAD];

  const int bx = blockIdx.x;
  const int hx = (bx & 7) * 28 + (bx >> 3);   // XCD-aware swizzle (bijective, 224=28*8)
  const int ho = hx >> 1, half = hx & 1;
  const int dd = blockIdx.y;
  const int bb = blockIdx.z;
  const int tid = threadIdx.x;
  const int lane = tid & 63;
  const int wv = tid >> 6;

  // ---- per-block k -> padded-plane row offset (ALWAYS valid; pads clamp) ----
  if (tid < KPAD) {
    const int k = (tid < KREAL) ? tid : (KREAL - 1);
    const int kd = k / C7, rem = k % C7, c = rem / 7, kh = rem % 7;
    offt[tid] = ((bb * C + c) * DP + 2 * dd + kd) * PLANE + (2 * ho + kh) * WP;
  }
  __syncthreads();

  // ---- stage: pair-units (kg, sp): one uint load = elements s,s+1 of row k ----
  {
    const int piwbase = half * 112;
    uint v4[NU2][4];
    int sbl[NU2], sbh[NU2];
#pragma unroll
    for (int i = 0; i < NU2; i++) {
      const int id = i * 512 + tid;
      const int kg = id >> 6, sp = id & 63;
      const int s = sp * 2;                       // even, 0..126
      const bool ok = (s < SROWS);
      const int piw = piwbase + s;
      const int4 ot = *reinterpret_cast<const int4*>(&offt[kg * 4]);
      v4[i][0] = *reinterpret_cast<const uint*>(in + (size_t)(ot.x + piw));
      v4[i][1] = *reinterpret_cast<const uint*>(in + (size_t)(ot.y + piw));
      v4[i][2] = *reinterpret_cast<const uint*>(in + (size_t)(ot.z + piw));
      v4[i][3] = *reinterpret_cast<const uint*>(in + (size_t)(ot.w + piw));
      const int m = (sp & 7) << 4;
      sbl[i] = ok ? ((s * ROWB + kg * 8) ^ m) : -1;
      sbh[i] = ok ? (((s + 1) * ROWB + kg * 8) ^ m) : -1;
    }
#pragma unroll
    for (int i = 0; i < NU2; i++) {
      if (sbl[i] >= 0) {
        ushort4 lo, hi;
        lo.x = (ushort)v4[i][0]; hi.x = (ushort)(v4[i][0] >> 16);
        lo.y = (ushort)v4[i][1]; hi.y = (ushort)(v4[i][1] >> 16);
        lo.z = (ushort)v4[i][2]; hi.z = (ushort)(v4[i][2] >> 16);
        lo.w = (ushort)v4[i][3]; hi.w = (ushort)(v4[i][3] >> 16);
        *reinterpret_cast<ushort4*>(smem + sbl[i]) = lo;   // row s
        *reinterpret_cast<ushort4*>(smem + sbh[i]) = hi;   // row s+1
      }
    }
  }
  __syncthreads();

  // ---- MFMA 32x32x16: wave (nh, kseg); kseg owns kw {2k,2k+1} (kseg3: {6}) ----
  const int nh = wv & 1, kseg = wv >> 1;
  const int l31 = lane & 31, khf = lane >> 5;

  int sbase[2];
#pragma unroll
  for (int mt = 0; mt < 2; mt++) {
    int wo_l = mt * 32 + l31;
    if (wo_l > 55) wo_l = 55;            // clamp; discarded in epilogue
    sbase[mt] = 2 * wo_l;
  }
  const ushort* wq = wB + (size_t)(nh * 32 + l31) * (7 * KPAD) + khf * 8;

  f32x16 acc[2] = {};

  const int kwbeg = kseg * 2;
  const int kwend = (kseg == 3) ? 7 : (kwbeg + 2);
  for (int kw = kwbeg; kw < kwend; kw++) {
#pragma unroll
    for (int ks = 0; ks < NKS; ks++) {
      const bf16x8 b = *reinterpret_cast<const bf16x8*>(wq + kw * KPAD + ks * 16);
#pragma unroll
      for (int mt = 0; mt < 2; mt++) {
        const int s = sbase[mt] + kw;
        const int byte = (s * ROWB + ks * 32 + khf * 16) ^ (((s >> 1) & 7) << 4);
        const bf16x8 a = *reinterpret_cast<const bf16x8*>(smem + byte);
        acc[mt] = __builtin_amdgcn_mfma_f32_32x32x16_bf16(a, b, acc[mt], 0, 0, 0);
      }
    }
  }

  // ---- cross-wave reduce: kseg{1,3} -> bufs; kseg{0,2} add; kseg2 -> buf; kseg0 adds ----
  __syncthreads();                       // staging LDS dead now
  float* buf0 = reinterpret_cast<float*>(smem);           // [4][16][64] f = 16KB
  float* buf1 = reinterpret_cast<float*>(smem + 16384);   // 16KB (total 32KB <= 37.7KB)
  if (kseg == 1) {
#pragma unroll
    for (int mt = 0; mt < 2; mt++)
#pragma unroll
      for (int r = 0; r < 16; r++)
        buf0[((nh * 2 + mt) * 16 + r) * 64 + lane] = acc[mt][r];
  }
  if (kseg == 3) {
#pragma unroll
    for (int mt = 0; mt < 2; mt++)
#pragma unroll
      for (int r = 0; r < 16; r++)
        buf1[((nh * 2 + mt) * 16 + r) * 64 + lane] = acc[mt][r];
  }
  __syncthreads();
  if (kseg == 0) {
#pragma unroll
    for (int mt = 0; mt < 2; mt++)
#pragma unroll
      for (int r = 0; r < 16; r++)
        acc[mt][r] += buf0[((nh * 2 + mt) * 16 + r) * 64 + lane];
  }
  if (kseg == 2) {
#pragma unroll
    for (int mt = 0; mt < 2; mt++)
#pragma unroll
      for (int r = 0; r < 16; r++)
        acc[mt][r] += buf1[((nh * 2 + mt) * 16 + r) * 64 + lane];
  }
  __syncthreads();
  if (kseg == 2) {
#pragma unroll
    for (int mt = 0; mt < 2; mt++)
#pragma unroll
      for (int r = 0; r < 16; r++)
        buf0[((nh * 2 + mt) * 16 + r) * 64 + lane] = acc[mt][r];
  }
  __syncthreads();
  if (kseg == 0) {
#pragma unroll
    for (int mt = 0; mt < 2; mt++)
#pragma unroll
      for (int r = 0; r < 16; r++)
        acc[mt][r] += buf0[((nh * 2 + mt) * 16 + r) * 64 + lane];
  }
  __syncthreads();

  ushort* eLDS = reinterpret_cast<ushort*>(smem);  // [64 oc][60] (overwrites bufs; synced)
  if (kseg == 0) {
    const int oc = nh * 32 + l31;
#pragma unroll
    for (int mt = 0; mt < 2; mt++) {
#pragma unroll
      for (int q = 0; q < 4; q++) {
        const int wo_b = mt * 32 + q * 8 + khf * 4;
        if (wo_b < 56) {
          ushort4 r4;
          r4.x = f2bf(fmaxf(acc[mt][q * 4 + 0], 0.f));
          r4.y = f2bf(fmaxf(acc[mt][q * 4 + 1], 0.f));
          r4.z = f2bf(fmaxf(acc[mt][q * 4 + 2], 0.f));
          r4.w = f2bf(fmaxf(acc[mt][q * 4 + 3], 0.f));
          *reinterpret_cast<ushort4*>(eLDS + oc * 60 + wo_b) = r4;
        }
      }
    }
  }
  __syncthreads();
  ushort* gout = out + ((size_t)(bb * 64) * DOUT + dd) * (HO * HO) + ho * HO + half * 56;
#pragma unroll
  for (int i = 0; i < 2; i++) {
    const int idx = i * 512 + tid;          // 64 oc x 14 w4 = 896
    if (idx < 896) {
      const int o2 = idx / 14;
      const int w4 = idx - o2 * 14;
      *reinterpret_cast<ushort4*>(gout + (size_t)o2 * DOUT * (HO * HO) + w4 * 4) =
          *reinterpret_cast<const ushort4*>(eLDS + o2 * 60 + w4 * 4);
    }
  }
}

// ---------------- fused maxpool 3x3 s2 SAME + gather into GEMM X layout (bf16) ----------------
// ushort2-vectorized: 2 consecutive wo per thread; zero-pad at iw=112 (safe post-ReLU).
__global__ void maxpool_gather(const ushort* __restrict__ in, ushort* __restrict__ X, int fbase) {
  const int idx = blockIdx.x * 256 + threadIdx.x;
  if (idx >= 2 * 64 * 8 * PO * 28) return;
  const int wo2 = idx % 28;
  const int ho = (idx / 28) % PO;
  const int rest = idx / (28 * PO);          // (b*64+c)*8+t
  const ushort* p = in + (size_t)rest * (HO * HO);
  const int iwb = wo2 * 4;                   // = 2*wo, wo = 2*wo2
  ushort m0 = 0, m1 = 0;
  for (int dh = 0; dh < 3; dh++) {
    const int ih = 2 * ho + dh;
    if (ih >= HO) break;
    const ushort* row = p + ih * HO;
    const ushort2 u0 = *reinterpret_cast<const ushort2*>(row + iwb);
    const ushort2 u1 = *reinterpret_cast<const ushort2*>(row + iwb + 2);
    const ushort e4 = (iwb + 4 < HO) ? row[iwb + 4] : (ushort)0;
    ushort a = (u0.x > u0.y) ? u0.x : u0.y;  a = (a > u1.x) ? a : u1.x;
    ushort b2 = (u1.x > u1.y) ? u1.x : u1.y; b2 = (b2 > e4) ? b2 : e4;
    m0 = (a > m0) ? a : m0;
    m1 = (b2 > m1) ? b2 : m1;
  }
  const int wo = wo2 * 2;
  const int t = rest % 8;
  const int c = (rest / 8) % 64;
  const int b = rest / 512;
  const int r = ((b * 8 + t) * 4 + ho / 14) * 4 + (wo / 14);
  const int f = fbase + c * 196 + (ho % 14) * 14 + (wo % 14);
  *reinterpret_cast<ushort2*>(X + (size_t)r * 25088 + f) = make_ushort2(m0, m1);
}

// ---------------- FCL1: X[256][25088] bf16 @ W1[25088][1024] f32(cvt in-kernel) -> part bf16 ----------------
// grid (bn=8, kc=98); BM=256 BN=128 BK=64, 4 kt per block
__global__ __launch_bounds__(512) void fcl1_mfma(
    const ushort* __restrict__ X, const float* __restrict__ W1, ushort* __restrict__ part)
{
  const int bn = blockIdx.x;
  const int kc = blockIdx.y;
  const int tid = threadIdx.x;
  const int lane = tid & 63;
  const int wv = tid >> 6;
  const int wm = wv >> 1, wn = wv & 1;
  const int l31 = lane & 31, kh = lane >> 5;

  __shared__ char xs[256 * 128];   // [r][64k] bf16, swz ((r&7)<<4)
  __shared__ char wsm[128 * 128];  // [n][64k] bf16, swz ((n&7)<<4)

  f32x16 acc[2][2] = {};

  const int kchunk0 = kc * 256;

  for (int kt = 0; kt < 4; kt++) {
    const int k0 = kchunk0 + kt * 64;
    __syncthreads();
#pragma unroll
    for (int i = 0; i < 4; i++) {
      const int chunk = tid + 512 * i;
      const int r = chunk >> 3, c8 = chunk & 7;
      const int4 v = *reinterpret_cast<const int4*>(X + (size_t)r * 25088 + k0 + c8 * 8);
      int byte = r * 128 + c8 * 16;
      byte ^= ((r & 7) << 4);
      *reinterpret_cast<int4*>(xs + byte) = v;
    }
    {
      const int nq = tid & 31, kp0 = tid >> 5;
#pragma unroll
      for (int h = 0; h < 2; h++) {
        const int kk = (kp0 + h * 16) * 2;
        const float4 a  = *reinterpret_cast<const float4*>(W1 + (size_t)(k0 + kk) * 1024 + bn * 128 + nq * 4);
        const float4 bq = *reinterpret_cast<const float4*>(W1 + (size_t)(k0 + kk + 1) * 1024 + bn * 128 + nq * 4);
        const float av[4] = {a.x, a.y, a.z, a.w};
        const float bv[4] = {bq.x, bq.y, bq.z, bq.w};
#pragma unroll
        for (int j = 0; j < 4; j++) {
          const int n = nq * 4 + j;
          const uint pack = (uint)f2bf(av[j]) | ((uint)f2bf(bv[j]) << 16);
          const int byte = (n * 128 + kk * 2) ^ ((n & 7) << 4);
          *reinterpret_cast<uint*>(wsm + byte) = pack;
        }
      }
    }
    __syncthreads();
#pragma unroll
    for (int ks = 0; ks < 4; ks++) {
      bf16x8 af[2], bfr[2];
#pragma unroll
      for (int m = 0; m < 2; m++) {
        const int r = wm * 64 + m * 32 + l31;
        const int byte = (r * 128 + ks * 32 + kh * 16) ^ ((r & 7) << 4);
        af[m] = *reinterpret_cast<const bf16x8*>(xs + byte);
      }
#pragma unroll
      for (int n = 0; n < 2; n++) {
        const int c = wn * 64 + n * 32 + l31;
        const int byte = (c * 128 + ks * 32 + kh * 16) ^ ((c & 7) << 4);
        bfr[n] = *reinterpret_cast<const bf16x8*>(wsm + byte);
      }
#pragma unroll
      for (int m = 0; m < 2; m++)
#pragma unroll
        for (int n = 0; n < 2; n++)
          acc[m][n] = __builtin_amdgcn_mfma_f32_32x32x16_bf16(af[m], bfr[n], acc[m][n], 0, 0, 0);
    }
  }

  ushort* pout = part + (size_t)kc * (256 * 1024);
#pragma unroll
  for (int m = 0; m < 2; m++)
#pragma unroll
    for (int n = 0; n < 2; n++)
#pragma unroll
      for (int rg = 0; rg < 16; rg++) {
        const int row = wm * 64 + m * 32 + (rg & 3) + 8 * (rg >> 2) + 4 * kh;
        const int col = bn * 128 + wn * 64 + n * 32 + l31;
        pout[(size_t)row * 1024 + col] = f2bf(acc[m][n][rg]);
      }
}

// h1 = relu(b1 + sum_kc part_bf16)
__global__ void h1_reduce(const ushort* __restrict__ part, const float* __restrict__ b1,
                          float* __restrict__ h1) {
  const int v = blockIdx.x * 256 + threadIdx.x;  // < 32768 = 256r x 128 n8
  if (v >= 32768) return;
  const int r = v >> 7, n8 = v & 127;
  float s[8];
#pragma unroll
  for (int j = 0; j < 8; j++) s[j] = b1[n8 * 8 + j];
  for (int kc = 0; kc < 98; kc++) {
    const u16x8 p = *reinterpret_cast<const u16x8*>(part + (size_t)kc * 262144 + r * 1024 + n8 * 8);
#pragma unroll
    for (int j = 0; j < 8; j++) s[j] += bf2f(p[j]);
  }
#pragma unroll
  for (int j = 0; j < 8; j++) h1[r * 1024 + n8 * 8 + j] = fmaxf(s[j], 0.f);
}

// h2 = relu(h1 @ W2 + b2): 4 rows per block
__global__ __launch_bounds__(256) void fcl2_k(const float* __restrict__ h1,
                                              const float* __restrict__ W2,
                                              const float* __restrict__ b2,
                                              float* __restrict__ h2) {
  const int r0 = blockIdx.x * 4;
  const int n = threadIdx.x;
  __shared__ float xr[4][1024];
  for (int i = threadIdx.x; i < 4096; i += 256) xr[i >> 10][i & 1023] = h1[r0 * 1024 + i];
  __syncthreads();
  float acc[4] = {b2[n], b2[n], b2[n], b2[n]};
  for (int k = 0; k < 1024; k++) {
    const float w = W2[k * 256 + n];
#pragma unroll
    for (int r = 0; r < 4; r++) acc[r] += xr[r][k] * w;
  }
#pragma unroll
  for (int r = 0; r < 4; r++) h2[(r0 + r) * 256 + n] = fmaxf(acc[r], 0.f);
}

__global__ void fcl3_k(const float* __restrict__ h2, const float* __restrict__ W3,
                       const float* __restrict__ b3, float* __restrict__ ms) {
  __shared__ float w[256];
  w[threadIdx.x] = W3[threadIdx.x];
  __syncthreads();
  const int r = threadIdx.x;
  float s = b3[0];
  for (int k = 0; k < 256; k++) s += h2[r * 256 + k] * w[k];
  ms[r] = 1.f / (1.f + expf(-s));
}

__global__ void upsample_k(const float* __restrict__ ms, float* __restrict__ mask) {
  const int idx = blockIdx.x * 256 + threadIdx.x;
  if (idx >= 2 * 16 * IHW * IHW) return;
  const int w = idx % IHW;
  const int h = (idx / IHW) % IHW;
  const int t = (idx / (IHW * IHW)) % 16;
  const int b = idx / (16 * IHW * IHW);

  const float tf = t * 0.5f - 0.25f;
  const float hf = (h + 0.5f) * (1.f / 56.f) - 0.5f;
  const float wf = (w + 0.5f) * (1.f / 56.f) - 0.5f;

  int t0 = (int)floorf(tf); const float ft = tf - t0;
  int h0 = (int)floorf(hf); const float fh = hf - h0;
  int w0 = (int)floorf(wf); const float fw = wf - w0;
  const int t1 = min(t0 + 1, 7); t0 = max(t0, 0);
  const int h1 = min(h0 + 1, 3); h0 = max(h0, 0);
  const int w1 = min(w0 + 1, 3); w0 = max(w0, 0);

  const float* p = ms + b * 128;
  auto at = [&](int tt, int hh, int ww) { return p[(tt * 4 + hh) * 4 + ww]; };
  const float c00 = at(t0, h0, w0) * (1.f - fw) + at(t0, h0, w1) * fw;
  const float c01 = at(t0, h1, w0) * (1.f - fw) + at(t0, h1, w1) * fw;
  const float c10 = at(t1, h0, w0) * (1.f - fw) + at(t1, h0, w1) * fw;
  const float c11 = at(t1, h1, w0) * (1.f - fw) + at(t1, h1, w1) * fw;
  const float c0 = c00 * (1.f - fh) + c01 * fh;
  const float c1 = c10 * (1.f - fh) + c11 * fh;
  mask[idx] = c0 * (1.f - ft) + c1 * ft;
}

// fused maxpool + spatial sum (bf16 in): one block per (head,b,oc,t) = 2048
__global__ __launch_bounds__(256) void pool_sum_k(const ushort* __restrict__ in,
                                                  float* __restrict__ psums) {
  const int blk = blockIdx.x;
  const ushort* p = in + (size_t)blk * (HO * HO);
  float s = 0.f;
  for (int idx = threadIdx.x; idx < PO * PO; idx += 256) {
    const int ho = idx / PO, wo = idx % PO;
    ushort m = 0;
    for (int dh = 0; dh < 3; dh++) {
      const int ih = 2 * ho + dh;
      if (ih >= HO) break;
      for (int dw = 0; dw < 3; dw++) {
        const int iw = 2 * wo + dw;
        if (iw >= HO) break;
        const ushort v = p[ih * HO + iw];
        m = (v > m) ? v : m;
      }
    }
    s += bf2f(m);
  }
  __shared__ float red[256];
  red[threadIdx.x] = s;
  __syncthreads();
  for (int off = 128; off > 0; off >>= 1) {
    if (threadIdx.x < off) red[threadIdx.x] += red[threadIdx.x + off];
    __syncthreads();
  }
  if (threadIdx.x == 0) psums[blk] = red[0];
}

// out[b_full*400 + l], b_full = head*2+b in [0,4)
__global__ void logits_k(const float* __restrict__ psums, const float* __restrict__ Wl,
                         const float* __restrict__ bl, float* __restrict__ out) {
  const int idx = blockIdx.x * 256 + threadIdx.x;
  if (idx >= 1600) return;
  const int bf = idx / 400, l = idx % 400;
  float s = bl[l];
  for (int oc = 0; oc < 64; oc++) {
    float ps = 0.f;
    for (int t = 0; t < 8; t++) ps += psums[(bf * 64 + oc) * 8 + t];
    s += (ps * (1.f / 25088.f)) * Wl[oc * 400 + l];
  }
  out[idx] = s;
}

extern "C" void kernel_launch(void* const* d_in, const int* in_sizes, int n_in,
                              void* d_out, int out_size, void* d_ws, size_t ws_size,
                              hipStream_t stream) {
  const float* rgbs   = (const float*)d_in[0];
  const float* flows  = (const float*)d_in[1];
  const float* bg     = (const float*)d_in[2];
  const float* w_rgb  = (const float*)d_in[3];
  const float* w_flow = (const float*)d_in[4];
  const float* w_feat = (const float*)d_in[5];
  const float* W1     = (const float*)d_in[6];
  const float* b1     = (const float*)d_in[7];
  const float* W2     = (const float*)d_in[8];
  const float* b2     = (const float*)d_in[9];
  const float* W3     = (const float*)d_in[10];
  const float* b3     = (const float*)d_in[11];
  const float* Wl     = (const float*)d_in[12];
  const float* bl     = (const float*)d_in[13];
  float* out = (float*)d_out;

  float* ws = (float*)d_ws;
  // A [0, 12845056)f: convbuf (bf16, up to z=4) / part (bf16, 98 chunks = exactly region A)
  ushort* convbuf = (ushort*)ws;
  ushort* part    = (ushort*)ws;                    // 25,690,112 ush
  // B [12845056, 16056320)f : X (6,422,528 ush)
  ushort* X       = (ushort*)(ws + 12845056);
  // C [16056320, ...)f : padded inputs; rgbsP+flowsP die after stems, maskedP aliases
  ushort* rgbsP   = (ushort*)(ws + 16056320);       // 6*21*232*240 = 7,015,680 ush
  ushort* flowsP  = (ushort*)(ws + 19564160);       // 4*21*232*240 = 4,677,120 ush
  ushort* maskedP = (ushort*)(ws + 16056320);       // 12*21*232*240 = 14,031,360 ush
  // tail
  float*  h1      = ws + 23100000;                  // 262,144
  float*  h2      = h1 + 262144;                    // 65,536
  float*  msmall  = h2 + 65536;                     // 256
  float*  psums   = msmall + 256;                   // 2048
  ushort* wrgb_b  = (ushort*)(psums + 2048);        // 71,680 ush (slot 86,016)
  ushort* wflow_b = wrgb_b + 86016;                 // 57,344 ush
  ushort* wfeat_b = wflow_b + 57344;                // 71,680 ush

  float* mask_full = out + 1600;

  // --- padded bf16 input prep + weight prep ---
  cvt_pad<<<(3507840 + 255) / 256, 256, 0, stream>>>(rgbs, rgbsP, 6);
  cvt_pad<<<(2338560 + 255) / 256, 256, 0, stream>>>(flows, flowsP, 4);
  wprep<3><<<(64 * 7 * 160 + 255) / 256, 256, 0, stream>>>(w_rgb, wrgb_b);
  wprep<2><<<(64 * 7 * 128 + 255) / 256, 256, 0, stream>>>(w_flow, wflow_b);
  wprep<3><<<(64 * 7 * 160 + 255) / 256, 256, 0, stream>>>(w_feat, wfeat_b);

  // --- mask branch stems ---
  conv_mfma<3><<<dim3(224, 8, 2), 512, 0, stream>>>(rgbsP, wrgb_b, convbuf);
  maxpool_gather<<<(1605632 + 255) / 256, 256, 0, stream>>>(convbuf, X, 0);
  conv_mfma<2><<<dim3(224, 8, 2), 512, 0, stream>>>(flowsP, wflow_b, convbuf);
  maxpool_gather<<<(1605632 + 255) / 256, 256, 0, stream>>>(convbuf, X, 12544);

  fcl1_mfma<<<dim3(8, 98), 512, 0, stream>>>(X, W1, part);
  h1_reduce<<<128, 256, 0, stream>>>(part, b1, h1);
  fcl2_k<<<64, 256, 0, stream>>>(h1, W2, b2, h2);
  fcl3_k<<<1, 256, 0, stream>>>(h2, W3, b3, msmall);
  upsample_k<<<(1605632 + 255) / 256, 256, 0, stream>>>(msmall, mask_full);

  // --- both feature heads merged ---
  masking_pad<<<(7015680 + 255) / 256, 256, 0, stream>>>(rgbs, mask_full, bg, maskedP);
  conv_mfma<3><<<dim3(224, 8, 4), 512, 0, stream>>>(maskedP, wfeat_b, convbuf);
  pool_sum_k<<<2048, 256, 0, stream>>>(convbuf, psums);
  logits_k<<<7, 256, 0, stream>>>(psums, Wl, bl, out);
}

// Round 21
// 447.446 us; speedup vs baseline: 1.1365x; 1.1365x over previous
//
#include <hip/hip_runtime.h>
#include <hip/hip_bf16.h>
#include <math.h>

#define IHW 224
#define DIN 16
#define DOUT 8
#define HO 112
#define PO 56
// padded input geometry: pid = 2dd+kd in [0,21), pih = 2ho+kh in [0,229)<232, piw in [0,240)
#define DP 21
#define HP 232
#define WP 240
#define PLANE (HP * WP)   // 55680

typedef __bf16 bf16x8 __attribute__((ext_vector_type(8)));
typedef float f32x4 __attribute__((ext_vector_type(4)));
typedef float f32x16 __attribute__((ext_vector_type(16)));
typedef ushort u16x8 __attribute__((ext_vector_type(8)));

__device__ __forceinline__ ushort f2bf(float f) {
  uint u = __float_as_uint(f);
  uint r = (u + 0x7FFFu + ((u >> 16) & 1u)) >> 16;
  return (ushort)r;
}
__device__ __forceinline__ float bf2f(ushort u) {
  return __uint_as_float(((uint)u) << 16);
}

// ---------------- f32 [bc][16][224][224] -> padded bf16 [bc][21][232][240] (zeros in pads) ----------------
__global__ void cvt_pad(const float* __restrict__ in, ushort* __restrict__ out, int nbc) {
  const int v = blockIdx.x * 256 + threadIdx.x;         // ushort2 units
  const int total = nbc * DP * HP * (WP / 2);
  if (v >= total) return;
  const int pw2 = v % (WP / 2);
  int rest = v / (WP / 2);
  const int pih = rest % HP; rest /= HP;
  const int pid = rest % DP;
  const int bc = rest / DP;
  const int id = pid - 2, ih = pih - 2;
  ushort2 o = make_ushort2(0, 0);
  if (id >= 0 && id < DIN && ih >= 0 && ih < IHW) {
    const float* src = in + ((size_t)(bc * DIN + id) * IHW + ih) * IHW;
    const int iw0 = pw2 * 2 - 2;
    if (iw0 >= 0 && iw0 < IHW) o.x = f2bf(src[iw0]);
    if (iw0 + 1 >= 0 && iw0 + 1 < IHW) o.y = f2bf(src[iw0 + 1]);
  }
  reinterpret_cast<ushort2*>(out)[v] = o;
}

// ---------------- masking + pad: out[head*6 + b*3 + c][pid][pih][piw] bf16 ----------------
__global__ void masking_pad(const float* __restrict__ rgbs, const float* __restrict__ mask,
                            const float* __restrict__ bg, ushort* __restrict__ out) {
  const int v = blockIdx.x * 256 + threadIdx.x;         // ushort2 units
  const int total = 12 * DP * HP * (WP / 2);
  if (v >= total) return;
  const int pw2 = v % (WP / 2);
  int rest = v / (WP / 2);
  const int pih = rest % HP; rest /= HP;
  const int pid = rest % DP;
  const int bc = rest / DP;
  const int head = bc / 6;
  const int r6 = bc - head * 6;
  const int b = r6 / 3, c = r6 - (r6 / 3) * 3;
  const int t = pid - 2, ih = pih - 2;
  ushort2 o = make_ushort2(0, 0);
  if (t >= 0 && t < DIN && ih >= 0 && ih < IHW) {
    const float* mrow = mask + ((size_t)(b * DIN + t)) * (IHW * IHW) + ih * IHW;
    const float* rrow = rgbs + ((size_t)((b * 3 + c) * DIN + t)) * (IHW * IHW) + ih * IHW;
    const float* brow = bg + (size_t)c * (IHW * IHW) + ih * IHW;
    const int iw0 = pw2 * 2 - 2;
#pragma unroll
    for (int j = 0; j < 2; j++) {
      const int iw = iw0 + j;
      if (iw >= 0 && iw < IHW) {
        float m = mrow[iw];
        if (head) m = 1.f - m;
        const float val = rrow[iw] * m + brow[iw] * (1.f - m);
        if (j == 0) o.x = f2bf(val); else o.y = f2bf(val);
      }
    }
  }
  reinterpret_cast<ushort2*>(out)[v] = o;
}

// ---------------- weight prep: f32 [64][C][7][7][7] -> bf16 [oc][kw][KPAD] ----------------
// k = kd*(C*7) + c*7 + kh  (zeros for k >= C*49)
template<int C>
__global__ __launch_bounds__(256) void wprep(const float* __restrict__ w, ushort* __restrict__ wB) {
  constexpr int C7 = C * 7, KREAL = C * 49, KPAD = (C == 3) ? 160 : 128;
  const int idx = blockIdx.x * 256 + threadIdx.x;
  if (idx >= 64 * 7 * KPAD) return;
  const int k = idx % KPAD;
  const int rest = idx / KPAD;
  const int kw = rest % 7;
  const int oc = rest / 7;
  float val = 0.f;
  if (k < KREAL) {
    const int kd = k / C7, rem = k % C7, c = rem / 7, kh = rem % 7;
    val = w[(((oc * C + c) * 7 + kd) * 7 + kh) * 7 + kw];
  }
  wB[idx] = f2bf(val);
}

// ---------------- conv3d 7x7x7 s2 SAME + ReLU via bf16 MFMA 32x32x16 ----------------
// block x XCD-swizzled: hx = (bx%8)*28 + bx/8. 256 thr = 4 waves = 2 nh x 2 kseg.
// Each wave computes BOTH mt tiles over half the kw range -> each B-frag loaded
// once per block (2x B reuse). Cross-wave partial reduce via LDS (one round).
template<int C>
__global__ __launch_bounds__(256, 4) void conv_mfma(
    const ushort* __restrict__ in, const ushort* __restrict__ wB,
    ushort* __restrict__ out)
{
  constexpr int C7 = C * 7, KREAL = C * 49;
  constexpr int KPAD = (C == 3) ? 160 : 128;
  constexpr int NKS = KPAD / 16;         // 10 / 8
  constexpr int ROWB = KPAD * 2;
  constexpr int KG = KPAD / 4;
  constexpr int SROWS = 118;
  constexpr int NU2 = KG * 64 / 256;     // pair-units/thread: 10 / 8
  constexpr int BAT = NU2 / 2;           // 5 / 4

  __shared__ char smem[SROWS * ROWB];    // 37,760B / 30,208B (also reduce buf + eLDS)
  __shared__ int offt[KPAD];

  const int bx = blockIdx.x;
  const int hx = (bx & 7) * 28 + (bx >> 3);   // XCD-aware swizzle (bijective, 224=28*8)
  const int ho = hx >> 1, half = hx & 1;
  const int dd = blockIdx.y;
  const int bb = blockIdx.z;
  const int tid = threadIdx.x;
  const int lane = tid & 63;
  const int wv = tid >> 6;

  // ---- per-block k -> padded-plane row offset (ALWAYS valid; pads clamp) ----
  if (tid < KPAD) {
    const int k = (tid < KREAL) ? tid : (KREAL - 1);
    const int kd = k / C7, rem = k % C7, c = rem / 7, kh = rem % 7;
    offt[tid] = ((bb * C + c) * DP + 2 * dd + kd) * PLANE + (2 * ho + kh) * WP;
  }
  __syncthreads();

  // ---- stage: pair-units (kg, sp): one uint load = elements s,s+1 of row k ----
  const int piwbase = half * 112;
  for (int itb = 0; itb < 2; itb++) {
    uint v4[BAT][4];
    int sbl[BAT], sbh[BAT];
#pragma unroll
    for (int i = 0; i < BAT; i++) {
      const int id = (itb * BAT + i) * 256 + tid;
      const int kg = id >> 6, sp = id & 63;
      const int s = sp * 2;                       // even, 0..126
      const bool ok = (s < SROWS);
      const int piw = piwbase + s;
      const int4 ot = *reinterpret_cast<const int4*>(&offt[kg * 4]);
      v4[i][0] = *reinterpret_cast<const uint*>(in + (size_t)(ot.x + piw));
      v4[i][1] = *reinterpret_cast<const uint*>(in + (size_t)(ot.y + piw));
      v4[i][2] = *reinterpret_cast<const uint*>(in + (size_t)(ot.z + piw));
      v4[i][3] = *reinterpret_cast<const uint*>(in + (size_t)(ot.w + piw));
      const int m = (sp & 7) << 4;
      sbl[i] = ok ? ((s * ROWB + kg * 8) ^ m) : -1;
      sbh[i] = ok ? (((s + 1) * ROWB + kg * 8) ^ m) : -1;
    }
#pragma unroll
    for (int i = 0; i < BAT; i++) {
      if (sbl[i] >= 0) {
        ushort4 lo, hi;
        lo.x = (ushort)v4[i][0]; hi.x = (ushort)(v4[i][0] >> 16);
        lo.y = (ushort)v4[i][1]; hi.y = (ushort)(v4[i][1] >> 16);
        lo.z = (ushort)v4[i][2]; hi.z = (ushort)(v4[i][2] >> 16);
        lo.w = (ushort)v4[i][3]; hi.w = (ushort)(v4[i][3] >> 16);
        *reinterpret_cast<ushort4*>(smem + sbl[i]) = lo;   // row s
        *reinterpret_cast<ushort4*>(smem + sbh[i]) = hi;   // row s+1
      }
    }
  }
  __syncthreads();

  // ---- MFMA 32x32x16: wave (nh, kseg); each wave does mt=0,1 over its kw range ----
  const int nh = wv & 1, kseg = wv >> 1;
  const int l31 = lane & 31, khf = lane >> 5;

  int sbase[2];
#pragma unroll
  for (int mt = 0; mt < 2; mt++) {
    int wo_l = mt * 32 + l31;
    if (wo_l > 55) wo_l = 55;            // clamp; discarded in epilogue
    sbase[mt] = 2 * wo_l;
  }
  const ushort* wq = wB + (size_t)(nh * 32 + l31) * (7 * KPAD) + khf * 8;

  f32x16 acc[2] = {};

  if (kseg == 0) {
#pragma unroll
    for (int kw = 0; kw < 4; kw++) {
#pragma unroll
      for (int ks = 0; ks < NKS; ks++) {
        const bf16x8 b = *reinterpret_cast<const bf16x8*>(wq + kw * KPAD + ks * 16);
#pragma unroll
        for (int mt = 0; mt < 2; mt++) {
          const int s = sbase[mt] + kw;
          const int byte = (s * ROWB + ks * 32 + khf * 16) ^ (((s >> 1) & 7) << 4);
          const bf16x8 a = *reinterpret_cast<const bf16x8*>(smem + byte);
          acc[mt] = __builtin_amdgcn_mfma_f32_32x32x16_bf16(a, b, acc[mt], 0, 0, 0);
        }
      }
    }
  } else {
#pragma unroll
    for (int kw = 4; kw < 7; kw++) {
#pragma unroll
      for (int ks = 0; ks < NKS; ks++) {
        const bf16x8 b = *reinterpret_cast<const bf16x8*>(wq + kw * KPAD + ks * 16);
#pragma unroll
        for (int mt = 0; mt < 2; mt++) {
          const int s = sbase[mt] + kw;
          const int byte = (s * ROWB + ks * 32 + khf * 16) ^ (((s >> 1) & 7) << 4);
          const bf16x8 a = *reinterpret_cast<const bf16x8*>(smem + byte);
          acc[mt] = __builtin_amdgcn_mfma_f32_32x32x16_bf16(a, b, acc[mt], 0, 0, 0);
        }
      }
    }
  }

  // ---- cross-wave reduce (kseg=1 partials -> kseg=0), then epilogue ----
  __syncthreads();                       // staging LDS dead now
  f32x16* red = reinterpret_cast<f32x16*>(smem);   // [nh*2+mt][64 lanes] = 16 KB
  if (kseg == 1) {
#pragma unroll
    for (int mt = 0; mt < 2; mt++) red[(nh * 2 + mt) * 64 + lane] = acc[mt];
  }
  __syncthreads();
  if (kseg == 0) {
#pragma unroll
    for (int mt = 0; mt < 2; mt++) {
      const f32x16 p = red[(nh * 2 + mt) * 64 + lane];
#pragma unroll
      for (int r = 0; r < 16; r++) acc[mt][r] += p[r];
    }
  }
  __syncthreads();

  ushort* eLDS = reinterpret_cast<ushort*>(smem);  // [64 oc][60] (overwrites red; synced)
  if (kseg == 0) {
    const int oc = nh * 32 + l31;
#pragma unroll
    for (int mt = 0; mt < 2; mt++) {
#pragma unroll
      for (int q = 0; q < 4; q++) {
        const int wo_b = mt * 32 + q * 8 + khf * 4;
        if (wo_b < 56) {
          ushort4 r4;
          r4.x = f2bf(fmaxf(acc[mt][q * 4 + 0], 0.f));
          r4.y = f2bf(fmaxf(acc[mt][q * 4 + 1], 0.f));
          r4.z = f2bf(fmaxf(acc[mt][q * 4 + 2], 0.f));
          r4.w = f2bf(fmaxf(acc[mt][q * 4 + 3], 0.f));
          *reinterpret_cast<ushort4*>(eLDS + oc * 60 + wo_b) = r4;
        }
      }
    }
  }
  __syncthreads();
  ushort* gout = out + ((size_t)(bb * 64) * DOUT + dd) * (HO * HO) + ho * HO + half * 56;
#pragma unroll
  for (int i = 0; i < 4; i++) {
    const int idx = i * 256 + tid;          // 64 oc x 14 w4 = 896
    if (idx < 896) {
      const int o2 = idx / 14;
      const int w4 = idx - o2 * 14;
      *reinterpret_cast<ushort4*>(gout + (size_t)o2 * DOUT * (HO * HO) + w4 * 4) =
          *reinterpret_cast<const ushort4*>(eLDS + o2 * 60 + w4 * 4);
    }
  }
}

// ---------------- fused maxpool 3x3 s2 SAME + gather into GEMM X layout (bf16) ----------------
// ushort2-vectorized: 2 consecutive wo per thread; zero-pad at iw=112 (safe post-ReLU).
__global__ void maxpool_gather(const ushort* __restrict__ in, ushort* __restrict__ X, int fbase) {
  const int idx = blockIdx.x * 256 + threadIdx.x;
  if (idx >= 2 * 64 * 8 * PO * 28) return;
  const int wo2 = idx % 28;
  const int ho = (idx / 28) % PO;
  const int rest = idx / (28 * PO);          // (b*64+c)*8+t
  const ushort* p = in + (size_t)rest * (HO * HO);
  const int iwb = wo2 * 4;                   // = 2*wo, wo = 2*wo2
  ushort m0 = 0, m1 = 0;
  for (int dh = 0; dh < 3; dh++) {
    const int ih = 2 * ho + dh;
    if (ih >= HO) break;
    const ushort* row = p + ih * HO;
    const ushort2 u0 = *reinterpret_cast<const ushort2*>(row + iwb);
    const ushort2 u1 = *reinterpret_cast<const ushort2*>(row + iwb + 2);
    const ushort e4 = (iwb + 4 < HO) ? row[iwb + 4] : (ushort)0;
    ushort a = (u0.x > u0.y) ? u0.x : u0.y;  a = (a > u1.x) ? a : u1.x;
    ushort b2 = (u1.x > u1.y) ? u1.x : u1.y; b2 = (b2 > e4) ? b2 : e4;
    m0 = (a > m0) ? a : m0;
    m1 = (b2 > m1) ? b2 : m1;
  }
  const int wo = wo2 * 2;
  const int t = rest % 8;
  const int c = (rest / 8) % 64;
  const int b = rest / 512;
  const int r = ((b * 8 + t) * 4 + ho / 14) * 4 + (wo / 14);
  const int f = fbase + c * 196 + (ho % 14) * 14 + (wo % 14);
  *reinterpret_cast<ushort2*>(X + (size_t)r * 25088 + f) = make_ushort2(m0, m1);
}

// ---------------- FCL1: X[256][25088] bf16 @ W1[25088][1024] f32(cvt in-kernel) -> part bf16 ----------------
// grid (bn=8, kc=98); BM=256 BN=128 BK=64, 4 kt per block
__global__ __launch_bounds__(512) void fcl1_mfma(
    const ushort* __restrict__ X, const float* __restrict__ W1, ushort* __restrict__ part)
{
  const int bn = blockIdx.x;
  const int kc = blockIdx.y;
  const int tid = threadIdx.x;
  const int lane = tid & 63;
  const int wv = tid >> 6;
  const int wm = wv >> 1, wn = wv & 1;
  const int l31 = lane & 31, kh = lane >> 5;

  __shared__ char xs[256 * 128];   // [r][64k] bf16, swz ((r&7)<<4)
  __shared__ char wsm[128 * 128];  // [n][64k] bf16, swz ((n&7)<<4)

  f32x16 acc[2][2] = {};

  const int kchunk0 = kc * 256;

  for (int kt = 0; kt < 4; kt++) {
    const int k0 = kchunk0 + kt * 64;
    __syncthreads();
#pragma unroll
    for (int i = 0; i < 4; i++) {
      const int chunk = tid + 512 * i;
      const int r = chunk >> 3, c8 = chunk & 7;
      const int4 v = *reinterpret_cast<const int4*>(X + (size_t)r * 25088 + k0 + c8 * 8);
      int byte = r * 128 + c8 * 16;
      byte ^= ((r & 7) << 4);
      *reinterpret_cast<int4*>(xs + byte) = v;
    }
    {
      const int nq = tid & 31, kp0 = tid >> 5;
#pragma unroll
      for (int h = 0; h < 2; h++) {
        const int kk = (kp0 + h * 16) * 2;
        const float4 a  = *reinterpret_cast<const float4*>(W1 + (size_t)(k0 + kk) * 1024 + bn * 128 + nq * 4);
        const float4 bq = *reinterpret_cast<const float4*>(W1 + (size_t)(k0 + kk + 1) * 1024 + bn * 128 + nq * 4);
        const float av[4] = {a.x, a.y, a.z, a.w};
        const float bv[4] = {bq.x, bq.y, bq.z, bq.w};
#pragma unroll
        for (int j = 0; j < 4; j++) {
          const int n = nq * 4 + j;
          const uint pack = (uint)f2bf(av[j]) | ((uint)f2bf(bv[j]) << 16);
          const int byte = (n * 128 + kk * 2) ^ ((n & 7) << 4);
          *reinterpret_cast<uint*>(wsm + byte) = pack;
        }
      }
    }
    __syncthreads();
#pragma unroll
    for (int ks = 0; ks < 4; ks++) {
      bf16x8 af[2], bfr[2];
#pragma unroll
      for (int m = 0; m < 2; m++) {
        const int r = wm * 64 + m * 32 + l31;
        const int byte = (r * 128 + ks * 32 + kh * 16) ^ ((r & 7) << 4);
        af[m] = *reinterpret_cast<const bf16x8*>(xs + byte);
      }
#pragma unroll
      for (int n = 0; n < 2; n++) {
        const int c = wn * 64 + n * 32 + l31;
        const int byte = (c * 128 + ks * 32 + kh * 16) ^ ((c & 7) << 4);
        bfr[n] = *reinterpret_cast<const bf16x8*>(wsm + byte);
      }
#pragma unroll
      for (int m = 0; m < 2; m++)
#pragma unroll
        for (int n = 0; n < 2; n++)
          acc[m][n] = __builtin_amdgcn_mfma_f32_32x32x16_bf16(af[m], bfr[n], acc[m][n], 0, 0, 0);
    }
  }

  ushort* pout = part + (size_t)kc * (256 * 1024);
#pragma unroll
  for (int m = 0; m < 2; m++)
#pragma unroll
    for (int n = 0; n < 2; n++)
#pragma unroll
      for (int rg = 0; rg < 16; rg++) {
        const int row = wm * 64 + m * 32 + (rg & 3) + 8 * (rg >> 2) + 4 * kh;
        const int col = bn * 128 + wn * 64 + n * 32 + l31;
        pout[(size_t)row * 1024 + col] = f2bf(acc[m][n][rg]);
      }
}

// h1 = relu(b1 + sum_kc part_bf16)
__global__ void h1_reduce(const ushort* __restrict__ part, const float* __restrict__ b1,
                          float* __restrict__ h1) {
  const int v = blockIdx.x * 256 + threadIdx.x;  // < 32768 = 256r x 128 n8
  if (v >= 32768) return;
  const int r = v >> 7, n8 = v & 127;
  float s[8];
#pragma unroll
  for (int j = 0; j < 8; j++) s[j] = b1[n8 * 8 + j];
  for (int kc = 0; kc < 98; kc++) {
    const u16x8 p = *reinterpret_cast<const u16x8*>(part + (size_t)kc * 262144 + r * 1024 + n8 * 8);
#pragma unroll
    for (int j = 0; j < 8; j++) s[j] += bf2f(p[j]);
  }
#pragma unroll
  for (int j = 0; j < 8; j++) h1[r * 1024 + n8 * 8 + j] = fmaxf(s[j], 0.f);
}

// h2 = relu(h1 @ W2 + b2): 4 rows per block
__global__ __launch_bounds__(256) void fcl2_k(const float* __restrict__ h1,
                                              const float* __restrict__ W2,
                                              const float* __restrict__ b2,
                                              float* __restrict__ h2) {
  const int r0 = blockIdx.x * 4;
  const int n = threadIdx.x;
  __shared__ float xr[4][1024];
  for (int i = threadIdx.x; i < 4096; i += 256) xr[i >> 10][i & 1023] = h1[r0 * 1024 + i];
  __syncthreads();
  float acc[4] = {b2[n], b2[n], b2[n], b2[n]};
  for (int k = 0; k < 1024; k++) {
    const float w = W2[k * 256 + n];
#pragma unroll
    for (int r = 0; r < 4; r++) acc[r] += xr[r][k] * w;
  }
#pragma unroll
  for (int r = 0; r < 4; r++) h2[(r0 + r) * 256 + n] = fmaxf(acc[r], 0.f);
}

__global__ void fcl3_k(const float* __restrict__ h2, const float* __restrict__ W3,
                       const float* __restrict__ b3, float* __restrict__ ms) {
  __shared__ float w[256];
  w[threadIdx.x] = W3[threadIdx.x];
  __syncthreads();
  const int r = threadIdx.x;
  float s = b3[0];
  for (int k = 0; k < 256; k++) s += h2[r * 256 + k] * w[k];
  ms[r] = 1.f / (1.f + expf(-s));
}

__global__ void upsample_k(const float* __restrict__ ms, float* __restrict__ mask) {
  const int idx = blockIdx.x * 256 + threadIdx.x;
  if (idx >= 2 * 16 * IHW * IHW) return;
  const int w = idx % IHW;
  const int h = (idx / IHW) % IHW;
  const int t = (idx / (IHW * IHW)) % 16;
  const int b = idx / (16 * IHW * IHW);

  const float tf = t * 0.5f - 0.25f;
  const float hf = (h + 0.5f) * (1.f / 56.f) - 0.5f;
  const float wf = (w + 0.5f) * (1.f / 56.f) - 0.5f;

  int t0 = (int)floorf(tf); const float ft = tf - t0;
  int h0 = (int)floorf(hf); const float fh = hf - h0;
  int w0 = (int)floorf(wf); const float fw = wf - w0;
  const int t1 = min(t0 + 1, 7); t0 = max(t0, 0);
  const int h1 = min(h0 + 1, 3); h0 = max(h0, 0);
  const int w1 = min(w0 + 1, 3); w0 = max(w0, 0);

  const float* p = ms + b * 128;
  auto at = [&](int tt, int hh, int ww) { return p[(tt * 4 + hh) * 4 + ww]; };
  const float c00 = at(t0, h0, w0) * (1.f - fw) + at(t0, h0, w1) * fw;
  const float c01 = at(t0, h1, w0) * (1.f - fw) + at(t0, h1, w1) * fw;
  const float c10 = at(t1, h0, w0) * (1.f - fw) + at(t1, h0, w1) * fw;
  const float c11 = at(t1, h1, w0) * (1.f - fw) + at(t1, h1, w1) * fw;
  const float c0 = c00 * (1.f - fh) + c01 * fh;
  const float c1 = c10 * (1.f - fh) + c11 * fh;
  mask[idx] = c0 * (1.f - ft) + c1 * ft;
}

// fused maxpool + spatial sum (bf16 in): one block per (head,b,oc,t) = 2048
__global__ __launch_bounds__(256) void pool_sum_k(const ushort* __restrict__ in,
                                                  float* __restrict__ psums) {
  const int blk = blockIdx.x;
  const ushort* p = in + (size_t)blk * (HO * HO);
  float s = 0.f;
  for (int idx = threadIdx.x; idx < PO * PO; idx += 256) {
    const int ho = idx / PO, wo = idx % PO;
    ushort m = 0;
    for (int dh = 0; dh < 3; dh++) {
      const int ih = 2 * ho + dh;
      if (ih >= HO) break;
      for (int dw = 0; dw < 3; dw++) {
        const int iw = 2 * wo + dw;
        if (iw >= HO) break;
        const ushort v = p[ih * HO + iw];
        m = (v > m) ? v : m;
      }
    }
    s += bf2f(m);
  }
  __shared__ float red[256];
  red[threadIdx.x] = s;
  __syncthreads();
  for (int off = 128; off > 0; off >>= 1) {
    if (threadIdx.x < off) red[threadIdx.x] += red[threadIdx.x + off];
    __syncthreads();
  }
  if (threadIdx.x == 0) psums[blk] = red[0];
}

// out[b_full*400 + l], b_full = head*2+b in [0,4)
__global__ void logits_k(const float* __restrict__ psums, const float* __restrict__ Wl,
                         const float* __restrict__ bl, float* __restrict__ out) {
  const int idx = blockIdx.x * 256 + threadIdx.x;
  if (idx >= 1600) return;
  const int bf = idx / 400, l = idx % 400;
  float s = bl[l];
  for (int oc = 0; oc < 64; oc++) {
    float ps = 0.f;
    for (int t = 0; t < 8; t++) ps += psums[(bf * 64 + oc) * 8 + t];
    s += (ps * (1.f / 25088.f)) * Wl[oc * 400 + l];
  }
  out[idx] = s;
}

extern "C" void kernel_launch(void* const* d_in, const int* in_sizes, int n_in,
                              void* d_out, int out_size, void* d_ws, size_t ws_size,
                              hipStream_t stream) {
  const float* rgbs   = (const float*)d_in[0];
  const float* flows  = (const float*)d_in[1];
  const float* bg     = (const float*)d_in[2];
  const float* w_rgb  = (const float*)d_in[3];
  const float* w_flow = (const float*)d_in[4];
  const float* w_feat = (const float*)d_in[5];
  const float* W1     = (const float*)d_in[6];
  const float* b1     = (const float*)d_in[7];
  const float* W2     = (const float*)d_in[8];
  const float* b2     = (const float*)d_in[9];
  const float* W3     = (const float*)d_in[10];
  const float* b3     = (const float*)d_in[11];
  const float* Wl     = (const float*)d_in[12];
  const float* bl     = (const float*)d_in[13];
  float* out = (float*)d_out;

  float* ws = (float*)d_ws;
  // A [0, 12845056)f: convbuf (bf16, up to z=4) / part (bf16, 98 chunks = exactly region A)
  ushort* convbuf = (ushort*)ws;
  ushort* part    = (ushort*)ws;                    // 25,690,112 ush
  // B [12845056, 16056320)f : X (6,422,528 ush)
  ushort* X       = (ushort*)(ws + 12845056);
  // C [16056320, ...)f : padded inputs; rgbsP+flowsP die after stems, maskedP aliases
  ushort* rgbsP   = (ushort*)(ws + 16056320);       // 6*21*232*240 = 7,015,680 ush
  ushort* flowsP  = (ushort*)(ws + 19564160);       // 4*21*232*240 = 4,677,120 ush
  ushort* maskedP = (ushort*)(ws + 16056320);       // 12*21*232*240 = 14,031,360 ush
  // tail
  float*  h1      = ws + 23100000;                  // 262,144
  float*  h2      = h1 + 262144;                    // 65,536
  float*  msmall  = h2 + 65536;                     // 256
  float*  psums   = msmall + 256;                   // 2048
  ushort* wrgb_b  = (ushort*)(psums + 2048);        // 71,680 ush (slot 86,016)
  ushort* wflow_b = wrgb_b + 86016;                 // 57,344 ush
  ushort* wfeat_b = wflow_b + 57344;                // 71,680 ush

  float* mask_full = out + 1600;

  // --- padded bf16 input prep + weight prep ---
  cvt_pad<<<(3507840 + 255) / 256, 256, 0, stream>>>(rgbs, rgbsP, 6);
  cvt_pad<<<(2338560 + 255) / 256, 256, 0, stream>>>(flows, flowsP, 4);
  wprep<3><<<(64 * 7 * 160 + 255) / 256, 256, 0, stream>>>(w_rgb, wrgb_b);
  wprep<2><<<(64 * 7 * 128 + 255) / 256, 256, 0, stream>>>(w_flow, wflow_b);
  wprep<3><<<(64 * 7 * 160 + 255) / 256, 256, 0, stream>>>(w_feat, wfeat_b);

  // --- mask branch stems ---
  conv_mfma<3><<<dim3(224, 8, 2), 256, 0, stream>>>(rgbsP, wrgb_b, convbuf);
  maxpool_gather<<<(1605632 + 255) / 256, 256, 0, stream>>>(convbuf, X, 0);
  conv_mfma<2><<<dim3(224, 8, 2), 256, 0, stream>>>(flowsP, wflow_b, convbuf);
  maxpool_gather<<<(1605632 + 255) / 256, 256, 0, stream>>>(convbuf, X, 12544);

  fcl1_mfma<<<dim3(8, 98), 512, 0, stream>>>(X, W1, part);
  h1_reduce<<<128, 256, 0, stream>>>(part, b1, h1);
  fcl2_k<<<64, 256, 0, stream>>>(h1, W2, b2, h2);
  fcl3_k<<<1, 256, 0, stream>>>(h2, W3, b3, msmall);
  upsample_k<<<(1605632 + 255) / 256, 256, 0, stream>>>(msmall, mask_full);

  // --- both feature heads merged ---
  masking_pad<<<(7015680 + 255) / 256, 256, 0, stream>>>(rgbs, mask_full, bg, maskedP);
  conv_mfma<3><<<dim3(224, 8, 4), 256, 0, stream>>>(maskedP, wfeat_b, convbuf);
  pool_sum_k<<<2048, 256, 0, stream>>>(convbuf, psums);
  logits_k<<<7, 256, 0, stream>>>(psums, Wl, bl, out);
}

// Round 22
// 441.426 us; speedup vs baseline: 1.1520x; 1.0136x over previous
//
#include <hip/hip_runtime.h>
#include <hip/hip_bf16.h>
#include <math.h>

#define IHW 224
#define DIN 16
#define DOUT 8
#define HO 112
#define PO 56
// padded input geometry: pid = 2dd+kd in [0,21), pih = 2ho+kh in [0,229)<232, piw in [0,240)
#define DP 21
#define HP 232
#define WP 240
#define PLANE (HP * WP)   // 55680

typedef __bf16 bf16x8 __attribute__((ext_vector_type(8)));
typedef float f32x4 __attribute__((ext_vector_type(4)));
typedef float f32x16 __attribute__((ext_vector_type(16)));
typedef ushort u16x8 __attribute__((ext_vector_type(8)));

__device__ __forceinline__ ushort f2bf(float f) {
  uint u = __float_as_uint(f);
  uint r = (u + 0x7FFFu + ((u >> 16) & 1u)) >> 16;
  return (ushort)r;
}
__device__ __forceinline__ float bf2f(ushort u) {
  return __uint_as_float(((uint)u) << 16);
}

// ---------------- fused pad-convert: rgbs(6 planes) + flows(4 planes) -> padded bf16, one launch ----------------
__global__ void cvt_pad2(const float* __restrict__ rgbs, const float* __restrict__ flows,
                         ushort* __restrict__ out) {
  const int v = blockIdx.x * 256 + threadIdx.x;         // ushort2 units
  const int total = 10 * DP * HP * (WP / 2);
  if (v >= total) return;
  const int pw2 = v % (WP / 2);
  int rest = v / (WP / 2);
  const int pih = rest % HP; rest /= HP;
  const int pid = rest % DP;
  const int bc = rest / DP;
  const int id = pid - 2, ih = pih - 2;
  ushort2 o = make_ushort2(0, 0);
  if (id >= 0 && id < DIN && ih >= 0 && ih < IHW) {
    const float* base = (bc < 6) ? (rgbs + (size_t)bc * DIN * IHW * IHW)
                                 : (flows + (size_t)(bc - 6) * DIN * IHW * IHW);
    const float* src = base + ((size_t)id * IHW + ih) * IHW;
    const int iw0 = pw2 * 2 - 2;
    if (iw0 >= 0 && iw0 < IHW) o.x = f2bf(src[iw0]);
    if (iw0 + 1 >= 0 && iw0 + 1 < IHW) o.y = f2bf(src[iw0 + 1]);
  }
  reinterpret_cast<ushort2*>(out)[v] = o;
}

// ---------------- masking + pad with INLINE trilinear (no mask_full dependency) ----------------
// out[head*6 + b*3 + c][pid][pih][piw] bf16; ushort4 per thread
__global__ void masking_pad_f(const float* __restrict__ rgbs, const float* __restrict__ ms,
                              const float* __restrict__ bg, ushort* __restrict__ out) {
  __shared__ float ms_s[256];
  ms_s[threadIdx.x] = ms[threadIdx.x];
  __syncthreads();
  const int v = blockIdx.x * 256 + threadIdx.x;         // ushort4 units
  const int total = 12 * DP * HP * (WP / 4);
  if (v >= total) return;
  const int pw4 = v % (WP / 4);
  int rest = v / (WP / 4);
  const int pih = rest % HP; rest /= HP;
  const int pid = rest % DP;
  const int bc = rest / DP;
  const int head = bc / 6;
  const int r6 = bc - head * 6;
  const int b = r6 / 3, c = r6 - (r6 / 3) * 3;
  const int t = pid - 2, ih = pih - 2;
  ushort4 o = make_ushort4(0, 0, 0, 0);
  if (t >= 0 && t < DIN && ih >= 0 && ih < IHW) {
    const float* rrow = rgbs + ((size_t)((b * 3 + c) * DIN + t)) * (IHW * IHW) + ih * IHW;
    const float* brow = bg + (size_t)c * (IHW * IHW) + ih * IHW;
    // t/h interpolation terms (row-uniform)
    const float tf = t * 0.5f - 0.25f;
    const float hf = (ih + 0.5f) * (1.f / 56.f) - 0.5f;
    int t0 = (int)floorf(tf); const float ft = tf - t0;
    int h0 = (int)floorf(hf); const float fh = hf - h0;
    const int t1 = min(t0 + 1, 7); t0 = max(t0, 0);
    const int h1 = min(h0 + 1, 3); h0 = max(h0, 0);
    const float* p = ms_s + b * 128;
    const int iw0 = pw4 * 4 - 2;
    ushort res[4] = {0, 0, 0, 0};
#pragma unroll
    for (int j = 0; j < 4; j++) {
      const int iw = iw0 + j;
      if (iw >= 0 && iw < IHW) {
        const float wf = (iw + 0.5f) * (1.f / 56.f) - 0.5f;
        int w0 = (int)floorf(wf); const float fw = wf - w0;
        const int w1 = min(w0 + 1, 3); w0 = max(w0, 0);
        auto at = [&](int tt, int hh, int ww) { return p[(tt * 4 + hh) * 4 + ww]; };
        const float c00 = at(t0, h0, w0) * (1.f - fw) + at(t0, h0, w1) * fw;
        const float c01 = at(t0, h1, w0) * (1.f - fw) + at(t0, h1, w1) * fw;
        const float c10 = at(t1, h0, w0) * (1.f - fw) + at(t1, h0, w1) * fw;
        const float c11 = at(t1, h1, w0) * (1.f - fw) + at(t1, h1, w1) * fw;
        const float c0 = c00 * (1.f - fh) + c01 * fh;
        const float c1 = c10 * (1.f - fh) + c11 * fh;
        float m = c0 * (1.f - ft) + c1 * ft;
        if (head) m = 1.f - m;
        res[j] = f2bf(rrow[iw] * m + brow[iw] * (1.f - m));
      }
    }
    o = make_ushort4(res[0], res[1], res[2], res[3]);
  }
  reinterpret_cast<ushort4*>(out)[v] = o;
}

// ---------------- fused weight prep (3 tensors, one launch): f32 -> bf16 [oc][kw][KPAD] ----------------
template<int C>
__device__ __forceinline__ void wprep_one(const float* __restrict__ w, ushort* __restrict__ wB, int idx) {
  constexpr int C7 = C * 7, KREAL = C * 49, KPAD = (C == 3) ? 160 : 128;
  const int k = idx % KPAD;
  const int rest = idx / KPAD;
  const int kw = rest % 7;
  const int oc = rest / 7;
  float val = 0.f;
  if (k < KREAL) {
    const int kd = k / C7, rem = k % C7, c = rem / 7, kh = rem % 7;
    val = w[(((oc * C + c) * 7 + kd) * 7 + kh) * 7 + kw];
  }
  wB[idx] = f2bf(val);
}
__global__ __launch_bounds__(256) void wprep_all(
    const float* __restrict__ w_rgb, const float* __restrict__ w_flow, const float* __restrict__ w_feat,
    ushort* __restrict__ wrgb_b, ushort* __restrict__ wflow_b, ushort* __restrict__ wfeat_b) {
  const int idx = blockIdx.x * 256 + threadIdx.x;
  if (idx < 71680) wprep_one<3>(w_rgb, wrgb_b, idx);
  else if (idx < 71680 + 57344) wprep_one<2>(w_flow, wflow_b, idx - 71680);
  else if (idx < 71680 + 57344 + 71680) wprep_one<3>(w_feat, wfeat_b, idx - 129024);
}

// ---------------- conv3d 7x7x7 s2 SAME + ReLU via bf16 MFMA 32x32x16 (R18-validated) ----------------
// block x XCD-swizzled: hx = (bx%8)*28 + bx/8. 256 thr = 4 waves = 2 nh x 2 kseg.
// Each wave computes BOTH mt tiles over half the kw range -> each B-frag loaded
// once per block (2x B reuse). Cross-wave partial reduce via LDS (one round).
template<int C>
__global__ __launch_bounds__(256, 4) void conv_mfma(
    const ushort* __restrict__ in, const ushort* __restrict__ wB,
    ushort* __restrict__ out)
{
  constexpr int C7 = C * 7, KREAL = C * 49;
  constexpr int KPAD = (C == 3) ? 160 : 128;
  constexpr int NKS = KPAD / 16;         // 10 / 8
  constexpr int ROWB = KPAD * 2;
  constexpr int KG = KPAD / 4;
  constexpr int SROWS = 118;
  constexpr int NU2 = KG * 64 / 256;     // pair-units/thread: 10 / 8
  constexpr int BAT = NU2 / 2;           // 5 / 4

  __shared__ char smem[SROWS * ROWB];    // 37,760B / 30,208B (also reduce buf + eLDS)
  __shared__ int offt[KPAD];

  const int bx = blockIdx.x;
  const int hx = (bx & 7) * 28 + (bx >> 3);   // XCD-aware swizzle (bijective, 224=28*8)
  const int ho = hx >> 1, half = hx & 1;
  const int dd = blockIdx.y;
  const int bb = blockIdx.z;
  const int tid = threadIdx.x;
  const int lane = tid & 63;
  const int wv = tid >> 6;

  // ---- per-block k -> padded-plane row offset (ALWAYS valid; pads clamp) ----
  if (tid < KPAD) {
    const int k = (tid < KREAL) ? tid : (KREAL - 1);
    const int kd = k / C7, rem = k % C7, c = rem / 7, kh = rem % 7;
    offt[tid] = ((bb * C + c) * DP + 2 * dd + kd) * PLANE + (2 * ho + kh) * WP;
  }
  __syncthreads();

  // ---- stage: pair-units (kg, sp): one uint load = elements s,s+1 of row k ----
  const int piwbase = half * 112;
  for (int itb = 0; itb < 2; itb++) {
    uint v4[BAT][4];
    int sbl[BAT], sbh[BAT];
#pragma unroll
    for (int i = 0; i < BAT; i++) {
      const int id = (itb * BAT + i) * 256 + tid;
      const int kg = id >> 6, sp = id & 63;
      const int s = sp * 2;                       // even, 0..126
      const bool ok = (s < SROWS);
      const int piw = piwbase + s;
      const int4 ot = *reinterpret_cast<const int4*>(&offt[kg * 4]);
      v4[i][0] = *reinterpret_cast<const uint*>(in + (size_t)(ot.x + piw));
      v4[i][1] = *reinterpret_cast<const uint*>(in + (size_t)(ot.y + piw));
      v4[i][2] = *reinterpret_cast<const uint*>(in + (size_t)(ot.z + piw));
      v4[i][3] = *reinterpret_cast<const uint*>(in + (size_t)(ot.w + piw));
      const int m = (sp & 7) << 4;
      sbl[i] = ok ? ((s * ROWB + kg * 8) ^ m) : -1;
      sbh[i] = ok ? (((s + 1) * ROWB + kg * 8) ^ m) : -1;
    }
#pragma unroll
    for (int i = 0; i < BAT; i++) {
      if (sbl[i] >= 0) {
        ushort4 lo, hi;
        lo.x = (ushort)v4[i][0]; hi.x = (ushort)(v4[i][0] >> 16);
        lo.y = (ushort)v4[i][1]; hi.y = (ushort)(v4[i][1] >> 16);
        lo.z = (ushort)v4[i][2]; hi.z = (ushort)(v4[i][2] >> 16);
        lo.w = (ushort)v4[i][3]; hi.w = (ushort)(v4[i][3] >> 16);
        *reinterpret_cast<ushort4*>(smem + sbl[i]) = lo;   // row s
        *reinterpret_cast<ushort4*>(smem + sbh[i]) = hi;   // row s+1
      }
    }
  }
  __syncthreads();

  // ---- MFMA 32x32x16: wave (nh, kseg); each wave does mt=0,1 over its kw range ----
  const int nh = wv & 1, kseg = wv >> 1;
  const int l31 = lane & 31, khf = lane >> 5;

  int sbase[2];
#pragma unroll
  for (int mt = 0; mt < 2; mt++) {
    int wo_l = mt * 32 + l31;
    if (wo_l > 55) wo_l = 55;            // clamp; discarded in epilogue
    sbase[mt] = 2 * wo_l;
  }
  const ushort* wq = wB + (size_t)(nh * 32 + l31) * (7 * KPAD) + khf * 8;

  f32x16 acc[2] = {};

  if (kseg == 0) {
#pragma unroll
    for (int kw = 0; kw < 4; kw++) {
#pragma unroll
      for (int ks = 0; ks < NKS; ks++) {
        const bf16x8 b = *reinterpret_cast<const bf16x8*>(wq + kw * KPAD + ks * 16);
#pragma unroll
        for (int mt = 0; mt < 2; mt++) {
          const int s = sbase[mt] + kw;
          const int byte = (s * ROWB + ks * 32 + khf * 16) ^ (((s >> 1) & 7) << 4);
          const bf16x8 a = *reinterpret_cast<const bf16x8*>(smem + byte);
          acc[mt] = __builtin_amdgcn_mfma_f32_32x32x16_bf16(a, b, acc[mt], 0, 0, 0);
        }
      }
    }
  } else {
#pragma unroll
    for (int kw = 4; kw < 7; kw++) {
#pragma unroll
      for (int ks = 0; ks < NKS; ks++) {
        const bf16x8 b = *reinterpret_cast<const bf16x8*>(wq + kw * KPAD + ks * 16);
#pragma unroll
        for (int mt = 0; mt < 2; mt++) {
          const int s = sbase[mt] + kw;
          const int byte = (s * ROWB + ks * 32 + khf * 16) ^ (((s >> 1) & 7) << 4);
          const bf16x8 a = *reinterpret_cast<const bf16x8*>(smem + byte);
          acc[mt] = __builtin_amdgcn_mfma_f32_32x32x16_bf16(a, b, acc[mt], 0, 0, 0);
        }
      }
    }
  }

  // ---- cross-wave reduce (kseg=1 partials -> kseg=0), then epilogue ----
  __syncthreads();                       // staging LDS dead now
  f32x16* red = reinterpret_cast<f32x16*>(smem);   // [nh*2+mt][64 lanes] = 16 KB
  if (kseg == 1) {
#pragma unroll
    for (int mt = 0; mt < 2; mt++) red[(nh * 2 + mt) * 64 + lane] = acc[mt];
  }
  __syncthreads();
  if (kseg == 0) {
#pragma unroll
    for (int mt = 0; mt < 2; mt++) {
      const f32x16 p = red[(nh * 2 + mt) * 64 + lane];
#pragma unroll
      for (int r = 0; r < 16; r++) acc[mt][r] += p[r];
    }
  }
  __syncthreads();

  ushort* eLDS = reinterpret_cast<ushort*>(smem);  // [64 oc][60] (overwrites red; synced)
  if (kseg == 0) {
    const int oc = nh * 32 + l31;
#pragma unroll
    for (int mt = 0; mt < 2; mt++) {
#pragma unroll
      for (int q = 0; q < 4; q++) {
        const int wo_b = mt * 32 + q * 8 + khf * 4;
        if (wo_b < 56) {
          ushort4 r4;
          r4.x = f2bf(fmaxf(acc[mt][q * 4 + 0], 0.f));
          r4.y = f2bf(fmaxf(acc[mt][q * 4 + 1], 0.f));
          r4.z = f2bf(fmaxf(acc[mt][q * 4 + 2], 0.f));
          r4.w = f2bf(fmaxf(acc[mt][q * 4 + 3], 0.f));
          *reinterpret_cast<ushort4*>(eLDS + oc * 60 + wo_b) = r4;
        }
      }
    }
  }
  __syncthreads();
  ushort* gout = out + ((size_t)(bb * 64) * DOUT + dd) * (HO * HO) + ho * HO + half * 56;
#pragma unroll
  for (int i = 0; i < 4; i++) {
    const int idx = i * 256 + tid;          // 64 oc x 14 w4 = 896
    if (idx < 896) {
      const int o2 = idx / 14;
      const int w4 = idx - o2 * 14;
      *reinterpret_cast<ushort4*>(gout + (size_t)o2 * DOUT * (HO * HO) + w4 * 4) =
          *reinterpret_cast<const ushort4*>(eLDS + o2 * 60 + w4 * 4);
    }
  }
}

// ---------------- fused maxpool 3x3 s2 SAME + gather into GEMM X layout (bf16) ----------------
// ushort2-vectorized: 2 consecutive wo per thread; zero-pad at iw=112 (safe post-ReLU).
__global__ void maxpool_gather(const ushort* __restrict__ in, ushort* __restrict__ X, int fbase) {
  const int idx = blockIdx.x * 256 + threadIdx.x;
  if (idx >= 2 * 64 * 8 * PO * 28) return;
  const int wo2 = idx % 28;
  const int ho = (idx / 28) % PO;
  const int rest = idx / (28 * PO);          // (b*64+c)*8+t
  const ushort* p = in + (size_t)rest * (HO * HO);
  const int iwb = wo2 * 4;                   // = 2*wo, wo = 2*wo2
  ushort m0 = 0, m1 = 0;
  for (int dh = 0; dh < 3; dh++) {
    const int ih = 2 * ho + dh;
    if (ih >= HO) break;
    const ushort* row = p + ih * HO;
    const ushort2 u0 = *reinterpret_cast<const ushort2*>(row + iwb);
    const ushort2 u1 = *reinterpret_cast<const ushort2*>(row + iwb + 2);
    const ushort e4 = (iwb + 4 < HO) ? row[iwb + 4] : (ushort)0;
    ushort a = (u0.x > u0.y) ? u0.x : u0.y;  a = (a > u1.x) ? a : u1.x;
    ushort b2 = (u1.x > u1.y) ? u1.x : u1.y; b2 = (b2 > e4) ? b2 : e4;
    m0 = (a > m0) ? a : m0;
    m1 = (b2 > m1) ? b2 : m1;
  }
  const int wo = wo2 * 2;
  const int t = rest % 8;
  const int c = (rest / 8) % 64;
  const int b = rest / 512;
  const int r = ((b * 8 + t) * 4 + ho / 14) * 4 + (wo / 14);
  const int f = fbase + c * 196 + (ho % 14) * 14 + (wo % 14);
  *reinterpret_cast<ushort2*>(X + (size_t)r * 25088 + f) = make_ushort2(m0, m1);
}

// ---------------- FCL1: X[256][25088] bf16 @ W1[25088][1024] f32(cvt in-kernel) -> part bf16 ----------------
// grid (bn=8, kc=98); BM=256 BN=128 BK=64, 4 kt per block
__global__ __launch_bounds__(512) void fcl1_mfma(
    const ushort* __restrict__ X, const float* __restrict__ W1, ushort* __restrict__ part)
{
  const int bn = blockIdx.x;
  const int kc = blockIdx.y;
  const int tid = threadIdx.x;
  const int lane = tid & 63;
  const int wv = tid >> 6;
  const int wm = wv >> 1, wn = wv & 1;
  const int l31 = lane & 31, kh = lane >> 5;

  __shared__ char xs[256 * 128];   // [r][64k] bf16, swz ((r&7)<<4)
  __shared__ char wsm[128 * 128];  // [n][64k] bf16, swz ((n&7)<<4)

  f32x16 acc[2][2] = {};

  const int kchunk0 = kc * 256;

  for (int kt = 0; kt < 4; kt++) {
    const int k0 = kchunk0 + kt * 64;
    __syncthreads();
#pragma unroll
    for (int i = 0; i < 4; i++) {
      const int chunk = tid + 512 * i;
      const int r = chunk >> 3, c8 = chunk & 7;
      const int4 v = *reinterpret_cast<const int4*>(X + (size_t)r * 25088 + k0 + c8 * 8);
      int byte = r * 128 + c8 * 16;
      byte ^= ((r & 7) << 4);
      *reinterpret_cast<int4*>(xs + byte) = v;
    }
    {
      const int nq = tid & 31, kp0 = tid >> 5;
#pragma unroll
      for (int h = 0; h < 2; h++) {
        const int kk = (kp0 + h * 16) * 2;
        const float4 a  = *reinterpret_cast<const float4*>(W1 + (size_t)(k0 + kk) * 1024 + bn * 128 + nq * 4);
        const float4 bq = *reinterpret_cast<const float4*>(W1 + (size_t)(k0 + kk + 1) * 1024 + bn * 128 + nq * 4);
        const float av[4] = {a.x, a.y, a.z, a.w};
        const float bv[4] = {bq.x, bq.y, bq.z, bq.w};
#pragma unroll
        for (int j = 0; j < 4; j++) {
          const int n = nq * 4 + j;
          const uint pack = (uint)f2bf(av[j]) | ((uint)f2bf(bv[j]) << 16);
          const int byte = (n * 128 + kk * 2) ^ ((n & 7) << 4);
          *reinterpret_cast<uint*>(wsm + byte) = pack;
        }
      }
    }
    __syncthreads();
#pragma unroll
    for (int ks = 0; ks < 4; ks++) {
      bf16x8 af[2], bfr[2];
#pragma unroll
      for (int m = 0; m < 2; m++) {
        const int r = wm * 64 + m * 32 + l31;
        const int byte = (r * 128 + ks * 32 + kh * 16) ^ ((r & 7) << 4);
        af[m] = *reinterpret_cast<const bf16x8*>(xs + byte);
      }
#pragma unroll
      for (int n = 0; n < 2; n++) {
        const int c = wn * 64 + n * 32 + l31;
        const int byte = (c * 128 + ks * 32 + kh * 16) ^ ((c & 7) << 4);
        bfr[n] = *reinterpret_cast<const bf16x8*>(wsm + byte);
      }
#pragma unroll
      for (int m = 0; m < 2; m++)
#pragma unroll
        for (int n = 0; n < 2; n++)
          acc[m][n] = __builtin_amdgcn_mfma_f32_32x32x16_bf16(af[m], bfr[n], acc[m][n], 0, 0, 0);
    }
  }

  ushort* pout = part + (size_t)kc * (256 * 1024);
#pragma unroll
  for (int m = 0; m < 2; m++)
#pragma unroll
    for (int n = 0; n < 2; n++)
#pragma unroll
      for (int rg = 0; rg < 16; rg++) {
        const int row = wm * 64 + m * 32 + (rg & 3) + 8 * (rg >> 2) + 4 * kh;
        const int col = bn * 128 + wn * 64 + n * 32 + l31;
        pout[(size_t)row * 1024 + col] = f2bf(acc[m][n][rg]);
      }
}

// h1 = relu(b1 + sum_kc part_bf16) — 256 blocks x 128 threads (full-GPU streaming)
__global__ __launch_bounds__(128) void h1_reduce(const ushort* __restrict__ part,
                                                 const float* __restrict__ b1,
                                                 float* __restrict__ h1) {
  const int v = blockIdx.x * 128 + threadIdx.x;  // < 32768 = 256r x 128 n8
  if (v >= 32768) return;
  const int r = v >> 7, n8 = v & 127;
  float s[8];
#pragma unroll
  for (int j = 0; j < 8; j++) s[j] = b1[n8 * 8 + j];
  for (int kc = 0; kc < 98; kc++) {
    const u16x8 p = *reinterpret_cast<const u16x8*>(part + (size_t)kc * 262144 + r * 1024 + n8 * 8);
#pragma unroll
    for (int j = 0; j < 8; j++) s[j] += bf2f(p[j]);
  }
#pragma unroll
  for (int j = 0; j < 8; j++) h1[r * 1024 + n8 * 8 + j] = fmaxf(s[j], 0.f);
}

// h2 = relu(h1 @ W2 + b2): 4 rows per block
__global__ __launch_bounds__(256) void fcl2_k(const float* __restrict__ h1,
                                              const float* __restrict__ W2,
                                              const float* __restrict__ b2,
                                              float* __restrict__ h2) {
  const int r0 = blockIdx.x * 4;
  const int n = threadIdx.x;
  __shared__ float xr[4][1024];
  for (int i = threadIdx.x; i < 4096; i += 256) xr[i >> 10][i & 1023] = h1[r0 * 1024 + i];
  __syncthreads();
  float acc[4] = {b2[n], b2[n], b2[n], b2[n]};
  for (int k = 0; k < 1024; k++) {
    const float w = W2[k * 256 + n];
#pragma unroll
    for (int r = 0; r < 4; r++) acc[r] += xr[r][k] * w;
  }
#pragma unroll
  for (int r = 0; r < 4; r++) h2[(r0 + r) * 256 + n] = fmaxf(acc[r], 0.f);
}

__global__ void fcl3_k(const float* __restrict__ h2, const float* __restrict__ W3,
                       const float* __restrict__ b3, float* __restrict__ ms) {
  __shared__ float w[256];
  w[threadIdx.x] = W3[threadIdx.x];
  __syncthreads();
  const int r = threadIdx.x;
  float s = b3[0];
  for (int k = 0; k < 256; k++) s += h2[r * 256 + k] * w[k];
  ms[r] = 1.f / (1.f + expf(-s));
}

// trilinear upsample: (2,8,4,4) -> (2,16,224,224) f32 (this IS the mask output)
__global__ void upsample_k(const float* __restrict__ ms, float* __restrict__ mask) {
  const int idx = blockIdx.x * 256 + threadIdx.x;
  if (idx >= 2 * 16 * IHW * IHW) return;
  const int w = idx % IHW;
  const int h = (idx / IHW) % IHW;
  const int t = (idx / (IHW * IHW)) % 16;
  const int b = idx / (16 * IHW * IHW);

  const float tf = t * 0.5f - 0.25f;
  const float hf = (h + 0.5f) * (1.f / 56.f) - 0.5f;
  const float wf = (w + 0.5f) * (1.f / 56.f) - 0.5f;

  int t0 = (int)floorf(tf); const float ft = tf - t0;
  int h0 = (int)floorf(hf); const float fh = hf - h0;
  int w0 = (int)floorf(wf); const float fw = wf - w0;
  const int t1 = min(t0 + 1, 7); t0 = max(t0, 0);
  const int h1 = min(h0 + 1, 3); h0 = max(h0, 0);
  const int w1 = min(w0 + 1, 3); w0 = max(w0, 0);

  const float* p = ms + b * 128;
  auto at = [&](int tt, int hh, int ww) { return p[(tt * 4 + hh) * 4 + ww]; };
  const float c00 = at(t0, h0, w0) * (1.f - fw) + at(t0, h0, w1) * fw;
  const float c01 = at(t0, h1, w0) * (1.f - fw) + at(t0, h1, w1) * fw;
  const float c10 = at(t1, h0, w0) * (1.f - fw) + at(t1, h0, w1) * fw;
  const float c11 = at(t1, h1, w0) * (1.f - fw) + at(t1, h1, w1) * fw;
  const float c0 = c00 * (1.f - fh) + c01 * fh;
  const float c1 = c10 * (1.f - fh) + c11 * fh;
  mask[idx] = c0 * (1.f - ft) + c1 * ft;
}

// fused maxpool + spatial sum (bf16 in): one block per (head,b,oc,t) = 2048
__global__ __launch_bounds__(256) void pool_sum_k(const ushort* __restrict__ in,
                                                  float* __restrict__ psums) {
  const int blk = blockIdx.x;
  const ushort* p = in + (size_t)blk * (HO * HO);
  float s = 0.f;
  for (int idx = threadIdx.x; idx < PO * PO; idx += 256) {
    const int ho = idx / PO, wo = idx % PO;
    ushort m = 0;
    for (int dh = 0; dh < 3; dh++) {
      const int ih = 2 * ho + dh;
      if (ih >= HO) break;
      for (int dw = 0; dw < 3; dw++) {
        const int iw = 2 * wo + dw;
        if (iw >= HO) break;
        const ushort v = p[ih * HO + iw];
        m = (v > m) ? v : m;
      }
    }
    s += bf2f(m);
  }
  __shared__ float red[256];
  red[threadIdx.x] = s;
  __syncthreads();
  for (int off = 128; off > 0; off >>= 1) {
    if (threadIdx.x < off) red[threadIdx.x] += red[threadIdx.x + off];
    __syncthreads();
  }
  if (threadIdx.x == 0) psums[blk] = red[0];
}

// out[b_full*400 + l], b_full = head*2+b in [0,4)
__global__ void logits_k(const float* __restrict__ psums, const float* __restrict__ Wl,
                         const float* __restrict__ bl, float* __restrict__ out) {
  const int idx = blockIdx.x * 256 + threadIdx.x;
  if (idx >= 1600) return;
  const int bf = idx / 400, l = idx % 400;
  float s = bl[l];
  for (int oc = 0; oc < 64; oc++) {
    float ps = 0.f;
    for (int t = 0; t < 8; t++) ps += psums[(bf * 64 + oc) * 8 + t];
    s += (ps * (1.f / 25088.f)) * Wl[oc * 400 + l];
  }
  out[idx] = s;
}

extern "C" void kernel_launch(void* const* d_in, const int* in_sizes, int n_in,
                              void* d_out, int out_size, void* d_ws, size_t ws_size,
                              hipStream_t stream) {
  const float* rgbs   = (const float*)d_in[0];
  const float* flows  = (const float*)d_in[1];
  const float* bg     = (const float*)d_in[2];
  const float* w_rgb  = (const float*)d_in[3];
  const float* w_flow = (const float*)d_in[4];
  const float* w_feat = (const float*)d_in[5];
  const float* W1     = (const float*)d_in[6];
  const float* b1     = (const float*)d_in[7];
  const float* W2     = (const float*)d_in[8];
  const float* b2     = (const float*)d_in[9];
  const float* W3     = (const float*)d_in[10];
  const float* b3     = (const float*)d_in[11];
  const float* Wl     = (const float*)d_in[12];
  const float* bl     = (const float*)d_in[13];
  float* out = (float*)d_out;

  float* ws = (float*)d_ws;
  // A [0, 12845056)f: convbuf (bf16, up to z=4) / part (bf16, 98 chunks = exactly region A)
  ushort* convbuf = (ushort*)ws;
  ushort* part    = (ushort*)ws;                    // 25,690,112 ush
  // B [12845056, 16056320)f : X (6,422,528 ush)
  ushort* X       = (ushort*)(ws + 12845056);
  // C [16056320, ...)f : padded inputs; rgbsP(+flowsP contiguous) die after stems, maskedP aliases
  ushort* rgbsP   = (ushort*)(ws + 16056320);       // 10*21*232*240 = 11,692,800 ush contiguous
  ushort* flowsP  = (ushort*)(ws + 19564160);       // = rgbsP + 7,015,680
  ushort* maskedP = (ushort*)(ws + 16056320);       // 12*21*232*240 = 14,031,360 ush
  // tail
  float*  h1      = ws + 23100000;                  // 262,144
  float*  h2      = h1 + 262144;                    // 65,536
  float*  msmall  = h2 + 65536;                     // 256
  float*  psums   = msmall + 256;                   // 2048
  ushort* wrgb_b  = (ushort*)(psums + 2048);        // 71,680 ush (slot 86,016)
  ushort* wflow_b = wrgb_b + 86016;                 // 57,344 ush
  ushort* wfeat_b = wflow_b + 57344;                // 71,680 ush

  float* mask_full = out + 1600;

  // --- padded bf16 input prep + weight prep (fused launches) ---
  cvt_pad2<<<(5846400 + 255) / 256, 256, 0, stream>>>(rgbs, flows, rgbsP);
  wprep_all<<<(200704 + 255) / 256, 256, 0, stream>>>(w_rgb, w_flow, w_feat,
                                                      wrgb_b, wflow_b, wfeat_b);

  // --- mask branch stems ---
  conv_mfma<3><<<dim3(224, 8, 2), 256, 0, stream>>>(rgbsP, wrgb_b, convbuf);
  maxpool_gather<<<(1605632 + 255) / 256, 256, 0, stream>>>(convbuf, X, 0);
  conv_mfma<2><<<dim3(224, 8, 2), 256, 0, stream>>>(flowsP, wflow_b, convbuf);
  maxpool_gather<<<(1605632 + 255) / 256, 256, 0, stream>>>(convbuf, X, 12544);

  fcl1_mfma<<<dim3(8, 98), 512, 0, stream>>>(X, W1, part);
  h1_reduce<<<256, 128, 0, stream>>>(part, b1, h1);
  fcl2_k<<<64, 256, 0, stream>>>(h1, W2, b2, h2);
  fcl3_k<<<1, 256, 0, stream>>>(h2, W3, b3, msmall);
  upsample_k<<<(1605632 + 255) / 256, 256, 0, stream>>>(msmall, mask_full);

  // --- both feature heads merged; masking computes trilinear inline (no mask_full dep) ---
  masking_pad_f<<<(3507840 + 255) / 256, 256, 0, stream>>>(rgbs, msmall, bg, maskedP);
  conv_mfma<3><<<dim3(224, 8, 4), 256, 0, stream>>>(maskedP, wfeat_b, convbuf);
  pool_sum_k<<<2048, 256, 0, stream>>>(convbuf, psums);
  logits_k<<<7, 256, 0, stream>>>(psums, Wl, bl, out);
}

// Round 23
// 438.126 us; speedup vs baseline: 1.1607x; 1.0075x over previous
//
#include <hip/hip_runtime.h>
#include <hip/hip_bf16.h>
#include <math.h>

#define IHW 224
#define DIN 16
#define DOUT 8
#define HO 112
#define PO 56
// padded input geometry: pid = 2dd+kd in [0,21), pih = 2ho+kh in [0,229)<232, piw in [0,240)
#define DP 21
#define HP 232
#define WP 240
#define PLANE (HP * WP)   // 55680

typedef __bf16 bf16x8 __attribute__((ext_vector_type(8)));
typedef float f32x4 __attribute__((ext_vector_type(4)));
typedef float f32x16 __attribute__((ext_vector_type(16)));
typedef ushort u16x8 __attribute__((ext_vector_type(8)));

__device__ __forceinline__ ushort f2bf(float f) {
  uint u = __float_as_uint(f);
  uint r = (u + 0x7FFFu + ((u >> 16) & 1u)) >> 16;
  return (ushort)r;
}
__device__ __forceinline__ float bf2f(ushort u) {
  return __uint_as_float(((uint)u) << 16);
}

// ---------------- fused pad-convert: rgbs(6 planes) + flows(4 planes) -> padded bf16, one launch ----------------
__global__ void cvt_pad2(const float* __restrict__ rgbs, const float* __restrict__ flows,
                         ushort* __restrict__ out) {
  const int v = blockIdx.x * 256 + threadIdx.x;         // ushort2 units
  const int total = 10 * DP * HP * (WP / 2);
  if (v >= total) return;
  const int pw2 = v % (WP / 2);
  int rest = v / (WP / 2);
  const int pih = rest % HP; rest /= HP;
  const int pid = rest % DP;
  const int bc = rest / DP;
  const int id = pid - 2, ih = pih - 2;
  ushort2 o = make_ushort2(0, 0);
  if (id >= 0 && id < DIN && ih >= 0 && ih < IHW) {
    const float* base = (bc < 6) ? (rgbs + (size_t)bc * DIN * IHW * IHW)
                                 : (flows + (size_t)(bc - 6) * DIN * IHW * IHW);
    const float* src = base + ((size_t)id * IHW + ih) * IHW;
    const int iw0 = pw2 * 2 - 2;
    if (iw0 >= 0 && iw0 < IHW) o.x = f2bf(src[iw0]);
    if (iw0 + 1 >= 0 && iw0 + 1 < IHW) o.y = f2bf(src[iw0 + 1]);
  }
  reinterpret_cast<ushort2*>(out)[v] = o;
}

// ---------------- masking + pad with INLINE trilinear (no mask_full dependency) ----------------
// out[head*6 + b*3 + c][pid][pih][piw] bf16; ushort4 per thread
__global__ void masking_pad_f(const float* __restrict__ rgbs, const float* __restrict__ ms,
                              const float* __restrict__ bg, ushort* __restrict__ out) {
  __shared__ float ms_s[256];
  ms_s[threadIdx.x] = ms[threadIdx.x];
  __syncthreads();
  const int v = blockIdx.x * 256 + threadIdx.x;         // ushort4 units
  const int total = 12 * DP * HP * (WP / 4);
  if (v >= total) return;
  const int pw4 = v % (WP / 4);
  int rest = v / (WP / 4);
  const int pih = rest % HP; rest /= HP;
  const int pid = rest % DP;
  const int bc = rest / DP;
  const int head = bc / 6;
  const int r6 = bc - head * 6;
  const int b = r6 / 3, c = r6 - (r6 / 3) * 3;
  const int t = pid - 2, ih = pih - 2;
  ushort4 o = make_ushort4(0, 0, 0, 0);
  if (t >= 0 && t < DIN && ih >= 0 && ih < IHW) {
    const float* rrow = rgbs + ((size_t)((b * 3 + c) * DIN + t)) * (IHW * IHW) + ih * IHW;
    const float* brow = bg + (size_t)c * (IHW * IHW) + ih * IHW;
    const float tf = t * 0.5f - 0.25f;
    const float hf = (ih + 0.5f) * (1.f / 56.f) - 0.5f;
    int t0 = (int)floorf(tf); const float ft = tf - t0;
    int h0 = (int)floorf(hf); const float fh = hf - h0;
    const int t1 = min(t0 + 1, 7); t0 = max(t0, 0);
    const int h1 = min(h0 + 1, 3); h0 = max(h0, 0);
    const float* p = ms_s + b * 128;
    const int iw0 = pw4 * 4 - 2;
    ushort res[4] = {0, 0, 0, 0};
#pragma unroll
    for (int j = 0; j < 4; j++) {
      const int iw = iw0 + j;
      if (iw >= 0 && iw < IHW) {
        const float wf = (iw + 0.5f) * (1.f / 56.f) - 0.5f;
        int w0 = (int)floorf(wf); const float fw = wf - w0;
        const int w1 = min(w0 + 1, 3); w0 = max(w0, 0);
        auto at = [&](int tt, int hh, int ww) { return p[(tt * 4 + hh) * 4 + ww]; };
        const float c00 = at(t0, h0, w0) * (1.f - fw) + at(t0, h0, w1) * fw;
        const float c01 = at(t0, h1, w0) * (1.f - fw) + at(t0, h1, w1) * fw;
        const float c10 = at(t1, h0, w0) * (1.f - fw) + at(t1, h0, w1) * fw;
        const float c11 = at(t1, h1, w0) * (1.f - fw) + at(t1, h1, w1) * fw;
        const float c0 = c00 * (1.f - fh) + c01 * fh;
        const float c1 = c10 * (1.f - fh) + c11 * fh;
        float m = c0 * (1.f - ft) + c1 * ft;
        if (head) m = 1.f - m;
        res[j] = f2bf(rrow[iw] * m + brow[iw] * (1.f - m));
      }
    }
    o = make_ushort4(res[0], res[1], res[2], res[3]);
  }
  reinterpret_cast<ushort4*>(out)[v] = o;
}

// ---------------- fused weight prep (3 tensors, one launch): f32 -> bf16 [oc][kw][KPAD] ----------------
template<int C>
__device__ __forceinline__ void wprep_one(const float* __restrict__ w, ushort* __restrict__ wB, int idx) {
  constexpr int C7 = C * 7, KREAL = C * 49, KPAD = (C == 3) ? 160 : 128;
  const int k = idx % KPAD;
  const int rest = idx / KPAD;
  const int kw = rest % 7;
  const int oc = rest / 7;
  float val = 0.f;
  if (k < KREAL) {
    const int kd = k / C7, rem = k % C7, c = rem / 7, kh = rem % 7;
    val = w[(((oc * C + c) * 7 + kd) * 7 + kh) * 7 + kw];
  }
  wB[idx] = f2bf(val);
}
__global__ __launch_bounds__(256) void wprep_all(
    const float* __restrict__ w_rgb, const float* __restrict__ w_flow, const float* __restrict__ w_feat,
    ushort* __restrict__ wrgb_b, ushort* __restrict__ wflow_b, ushort* __restrict__ wfeat_b) {
  const int idx = blockIdx.x * 256 + threadIdx.x;
  if (idx < 71680) wprep_one<3>(w_rgb, wrgb_b, idx);
  else if (idx < 71680 + 57344) wprep_one<2>(w_flow, wflow_b, idx - 71680);
  else if (idx < 71680 + 57344 + 71680) wprep_one<3>(w_feat, wfeat_b, idx - 129024);
}

// ---------------- conv3d 7x7x7 s2 SAME + ReLU via bf16 MFMA 32x32x16 (R18/R19-validated) ----------------
// block x XCD-swizzled: hx = (bx%8)*28 + bx/8. 256 thr = 4 waves = 2 nh x 2 kseg.
// Each wave computes BOTH mt tiles over half the kw range -> each B-frag loaded
// once per block (2x B reuse). Cross-wave reduce via conflict-free [w][r][lane].
template<int C>
__global__ __launch_bounds__(256, 4) void conv_mfma(
    const ushort* __restrict__ in, const ushort* __restrict__ wB,
    ushort* __restrict__ out)
{
  constexpr int C7 = C * 7, KREAL = C * 49;
  constexpr int KPAD = (C == 3) ? 160 : 128;
  constexpr int NKS = KPAD / 16;         // 10 / 8
  constexpr int ROWB = KPAD * 2;
  constexpr int KG = KPAD / 4;
  constexpr int SROWS = 118;
  constexpr int NU2 = KG * 64 / 256;     // pair-units/thread: 10 / 8
  constexpr int BAT = NU2 / 2;           // 5 / 4

  __shared__ char smem[SROWS * ROWB];    // 37,760B / 30,208B (also reduce buf + eLDS)
  __shared__ int offt[KPAD];

  const int bx = blockIdx.x;
  const int hx = (bx & 7) * 28 + (bx >> 3);   // XCD-aware swizzle (bijective, 224=28*8)
  const int ho = hx >> 1, half = hx & 1;
  const int dd = blockIdx.y;
  const int bb = blockIdx.z;
  const int tid = threadIdx.x;
  const int lane = tid & 63;
  const int wv = tid >> 6;

  // ---- per-block k -> padded-plane row offset (ALWAYS valid; pads clamp) ----
  if (tid < KPAD) {
    const int k = (tid < KREAL) ? tid : (KREAL - 1);
    const int kd = k / C7, rem = k % C7, c = rem / 7, kh = rem % 7;
    offt[tid] = ((bb * C + c) * DP + 2 * dd + kd) * PLANE + (2 * ho + kh) * WP;
  }
  __syncthreads();

  // ---- stage: pair-units (kg, sp): one uint load = elements s,s+1 of row k ----
  const int piwbase = half * 112;
  for (int itb = 0; itb < 2; itb++) {
    uint v4[BAT][4];
    int sbl[BAT], sbh[BAT];
#pragma unroll
    for (int i = 0; i < BAT; i++) {
      const int id = (itb * BAT + i) * 256 + tid;
      const int kg = id >> 6, sp = id & 63;
      const int s = sp * 2;                       // even, 0..126
      const bool ok = (s < SROWS);
      const int piw = piwbase + s;
      const int4 ot = *reinterpret_cast<const int4*>(&offt[kg * 4]);
      v4[i][0] = *reinterpret_cast<const uint*>(in + (size_t)(ot.x + piw));
      v4[i][1] = *reinterpret_cast<const uint*>(in + (size_t)(ot.y + piw));
      v4[i][2] = *reinterpret_cast<const uint*>(in + (size_t)(ot.z + piw));
      v4[i][3] = *reinterpret_cast<const uint*>(in + (size_t)(ot.w + piw));
      const int m = (sp & 7) << 4;
      sbl[i] = ok ? ((s * ROWB + kg * 8) ^ m) : -1;
      sbh[i] = ok ? (((s + 1) * ROWB + kg * 8) ^ m) : -1;
    }
#pragma unroll
    for (int i = 0; i < BAT; i++) {
      if (sbl[i] >= 0) {
        ushort4 lo, hi;
        lo.x = (ushort)v4[i][0]; hi.x = (ushort)(v4[i][0] >> 16);
        lo.y = (ushort)v4[i][1]; hi.y = (ushort)(v4[i][1] >> 16);
        lo.z = (ushort)v4[i][2]; hi.z = (ushort)(v4[i][2] >> 16);
        lo.w = (ushort)v4[i][3]; hi.w = (ushort)(v4[i][3] >> 16);
        *reinterpret_cast<ushort4*>(smem + sbl[i]) = lo;   // row s
        *reinterpret_cast<ushort4*>(smem + sbh[i]) = hi;   // row s+1
      }
    }
  }
  __syncthreads();

  // ---- MFMA 32x32x16: wave (nh, kseg); each wave does mt=0,1 over its kw range ----
  const int nh = wv & 1, kseg = wv >> 1;
  const int l31 = lane & 31, khf = lane >> 5;

  int sbase[2];
#pragma unroll
  for (int mt = 0; mt < 2; mt++) {
    int wo_l = mt * 32 + l31;
    if (wo_l > 55) wo_l = 55;            // clamp; discarded in epilogue
    sbase[mt] = 2 * wo_l;
  }
  const ushort* wq = wB + (size_t)(nh * 32 + l31) * (7 * KPAD) + khf * 8;

  f32x16 acc[2] = {};

  if (kseg == 0) {
#pragma unroll
    for (int kw = 0; kw < 4; kw++) {
#pragma unroll
      for (int ks = 0; ks < NKS; ks++) {
        const bf16x8 b = *reinterpret_cast<const bf16x8*>(wq + kw * KPAD + ks * 16);
#pragma unroll
        for (int mt = 0; mt < 2; mt++) {
          const int s = sbase[mt] + kw;
          const int byte = (s * ROWB + ks * 32 + khf * 16) ^ (((s >> 1) & 7) << 4);
          const bf16x8 a = *reinterpret_cast<const bf16x8*>(smem + byte);
          acc[mt] = __builtin_amdgcn_mfma_f32_32x32x16_bf16(a, b, acc[mt], 0, 0, 0);
        }
      }
    }
  } else {
#pragma unroll
    for (int kw = 4; kw < 7; kw++) {
#pragma unroll
      for (int ks = 0; ks < NKS; ks++) {
        const bf16x8 b = *reinterpret_cast<const bf16x8*>(wq + kw * KPAD + ks * 16);
#pragma unroll
        for (int mt = 0; mt < 2; mt++) {
          const int s = sbase[mt] + kw;
          const int byte = (s * ROWB + ks * 32 + khf * 16) ^ (((s >> 1) & 7) << 4);
          const bf16x8 a = *reinterpret_cast<const bf16x8*>(smem + byte);
          acc[mt] = __builtin_amdgcn_mfma_f32_32x32x16_bf16(a, b, acc[mt], 0, 0, 0);
        }
      }
    }
  }

  // ---- cross-wave reduce (kseg=1 partials -> kseg=0), conflict-free [w][r][lane] ----
  __syncthreads();                       // staging LDS dead now
  float* redf = reinterpret_cast<float*>(smem);    // [4][16][64] floats = 16 KB
  if (kseg == 1) {
#pragma unroll
    for (int mt = 0; mt < 2; mt++)
#pragma unroll
      for (int r = 0; r < 16; r++)
        redf[((nh * 2 + mt) * 16 + r) * 64 + lane] = acc[mt][r];
  }
  __syncthreads();
  if (kseg == 0) {
#pragma unroll
    for (int mt = 0; mt < 2; mt++)
#pragma unroll
      for (int r = 0; r < 16; r++)
        acc[mt][r] += redf[((nh * 2 + mt) * 16 + r) * 64 + lane];
  }
  __syncthreads();

  ushort* eLDS = reinterpret_cast<ushort*>(smem);  // [64 oc][60] (overwrites red; synced)
  if (kseg == 0) {
    const int oc = nh * 32 + l31;
#pragma unroll
    for (int mt = 0; mt < 2; mt++) {
#pragma unroll
      for (int q = 0; q < 4; q++) {
        const int wo_b = mt * 32 + q * 8 + khf * 4;
        if (wo_b < 56) {
          ushort4 r4;
          r4.x = f2bf(fmaxf(acc[mt][q * 4 + 0], 0.f));
          r4.y = f2bf(fmaxf(acc[mt][q * 4 + 1], 0.f));
          r4.z = f2bf(fmaxf(acc[mt][q * 4 + 2], 0.f));
          r4.w = f2bf(fmaxf(acc[mt][q * 4 + 3], 0.f));
          *reinterpret_cast<ushort4*>(eLDS + oc * 60 + wo_b) = r4;
        }
      }
    }
  }
  __syncthreads();
  ushort* gout = out + ((size_t)(bb * 64) * DOUT + dd) * (HO * HO) + ho * HO + half * 56;
#pragma unroll
  for (int i = 0; i < 4; i++) {
    const int idx = i * 256 + tid;          // 64 oc x 14 w4 = 896
    if (idx < 896) {
      const int o2 = idx / 14;
      const int w4 = idx - o2 * 14;
      *reinterpret_cast<ushort4*>(gout + (size_t)o2 * DOUT * (HO * HO) + w4 * 4) =
          *reinterpret_cast<const ushort4*>(eLDS + o2 * 60 + w4 * 4);
    }
  }
}

// ---------------- fused maxpool 3x3 s2 SAME + gather into GEMM X layout (bf16) ----------------
// ushort2-vectorized: 2 consecutive wo per thread; zero-pad at iw=112 (safe post-ReLU).
__global__ void maxpool_gather(const ushort* __restrict__ in, ushort* __restrict__ X, int fbase) {
  const int idx = blockIdx.x * 256 + threadIdx.x;
  if (idx >= 2 * 64 * 8 * PO * 28) return;
  const int wo2 = idx % 28;
  const int ho = (idx / 28) % PO;
  const int rest = idx / (28 * PO);          // (b*64+c)*8+t
  const ushort* p = in + (size_t)rest * (HO * HO);
  const int iwb = wo2 * 4;                   // = 2*wo, wo = 2*wo2
  ushort m0 = 0, m1 = 0;
  for (int dh = 0; dh < 3; dh++) {
    const int ih = 2 * ho + dh;
    if (ih >= HO) break;
    const ushort* row = p + ih * HO;
    const ushort2 u0 = *reinterpret_cast<const ushort2*>(row + iwb);
    const ushort2 u1 = *reinterpret_cast<const ushort2*>(row + iwb + 2);
    const ushort e4 = (iwb + 4 < HO) ? row[iwb + 4] : (ushort)0;
    ushort a = (u0.x > u0.y) ? u0.x : u0.y;  a = (a > u1.x) ? a : u1.x;
    ushort b2 = (u1.x > u1.y) ? u1.x : u1.y; b2 = (b2 > e4) ? b2 : e4;
    m0 = (a > m0) ? a : m0;
    m1 = (b2 > m1) ? b2 : m1;
  }
  const int wo = wo2 * 2;
  const int t = rest % 8;
  const int c = (rest / 8) % 64;
  const int b = rest / 512;
  const int r = ((b * 8 + t) * 4 + ho / 14) * 4 + (wo / 14);
  const int f = fbase + c * 196 + (ho % 14) * 14 + (wo % 14);
  *reinterpret_cast<ushort2*>(X + (size_t)r * 25088 + f) = make_ushort2(m0, m1);
}

// ---------------- FCL1: X[256][25088] bf16 @ W1[25088][1024] f32(cvt in-kernel) -> part bf16 ----------------
// grid (bn=8, kc=98); BM=256 BN=128 BK=64, 4 kt per block
__global__ __launch_bounds__(512) void fcl1_mfma(
    const ushort* __restrict__ X, const float* __restrict__ W1, ushort* __restrict__ part)
{
  const int bn = blockIdx.x;
  const int kc = blockIdx.y;
  const int tid = threadIdx.x;
  const int lane = tid & 63;
  const int wv = tid >> 6;
  const int wm = wv >> 1, wn = wv & 1;
  const int l31 = lane & 31, kh = lane >> 5;

  __shared__ char xs[256 * 128];   // [r][64k] bf16, swz ((r&7)<<4)
  __shared__ char wsm[128 * 128];  // [n][64k] bf16, swz ((n&7)<<4)

  f32x16 acc[2][2] = {};

  const int kchunk0 = kc * 256;

  for (int kt = 0; kt < 4; kt++) {
    const int k0 = kchunk0 + kt * 64;
    __syncthreads();
#pragma unroll
    for (int i = 0; i < 4; i++) {
      const int chunk = tid + 512 * i;
      const int r = chunk >> 3, c8 = chunk & 7;
      const int4 v = *reinterpret_cast<const int4*>(X + (size_t)r * 25088 + k0 + c8 * 8);
      int byte = r * 128 + c8 * 16;
      byte ^= ((r & 7) << 4);
      *reinterpret_cast<int4*>(xs + byte) = v;
    }
    {
      const int nq = tid & 31, kp0 = tid >> 5;
#pragma unroll
      for (int h = 0; h < 2; h++) {
        const int kk = (kp0 + h * 16) * 2;
        const float4 a  = *reinterpret_cast<const float4*>(W1 + (size_t)(k0 + kk) * 1024 + bn * 128 + nq * 4);
        const float4 bq = *reinterpret_cast<const float4*>(W1 + (size_t)(k0 + kk + 1) * 1024 + bn * 128 + nq * 4);
        const float av[4] = {a.x, a.y, a.z, a.w};
        const float bv[4] = {bq.x, bq.y, bq.z, bq.w};
#pragma unroll
        for (int j = 0; j < 4; j++) {
          const int n = nq * 4 + j;
          const uint pack = (uint)f2bf(av[j]) | ((uint)f2bf(bv[j]) << 16);
          const int byte = (n * 128 + kk * 2) ^ ((n & 7) << 4);
          *reinterpret_cast<uint*>(wsm + byte) = pack;
        }
      }
    }
    __syncthreads();
#pragma unroll
    for (int ks = 0; ks < 4; ks++) {
      bf16x8 af[2], bfr[2];
#pragma unroll
      for (int m = 0; m < 2; m++) {
        const int r = wm * 64 + m * 32 + l31;
        const int byte = (r * 128 + ks * 32 + kh * 16) ^ ((r & 7) << 4);
        af[m] = *reinterpret_cast<const bf16x8*>(xs + byte);
      }
#pragma unroll
      for (int n = 0; n < 2; n++) {
        const int c = wn * 64 + n * 32 + l31;
        const int byte = (c * 128 + ks * 32 + kh * 16) ^ ((c & 7) << 4);
        bfr[n] = *reinterpret_cast<const bf16x8*>(wsm + byte);
      }
#pragma unroll
      for (int m = 0; m < 2; m++)
#pragma unroll
        for (int n = 0; n < 2; n++)
          acc[m][n] = __builtin_amdgcn_mfma_f32_32x32x16_bf16(af[m], bfr[n], acc[m][n], 0, 0, 0);
    }
  }

  ushort* pout = part + (size_t)kc * (256 * 1024);
#pragma unroll
  for (int m = 0; m < 2; m++)
#pragma unroll
    for (int n = 0; n < 2; n++)
#pragma unroll
      for (int rg = 0; rg < 16; rg++) {
        const int row = wm * 64 + m * 32 + (rg & 3) + 8 * (rg >> 2) + 4 * kh;
        const int col = bn * 128 + wn * 64 + n * 32 + l31;
        pout[(size_t)row * 1024 + col] = f2bf(acc[m][n][rg]);
      }
}

// h1 = relu(b1 + sum_kc part_bf16) — 256 blocks x 128 threads (full-GPU streaming)
__global__ __launch_bounds__(128) void h1_reduce(const ushort* __restrict__ part,
                                                 const float* __restrict__ b1,
                                                 float* __restrict__ h1) {
  const int v = blockIdx.x * 128 + threadIdx.x;  // < 32768 = 256r x 128 n8
  if (v >= 32768) return;
  const int r = v >> 7, n8 = v & 127;
  float s[8];
#pragma unroll
  for (int j = 0; j < 8; j++) s[j] = b1[n8 * 8 + j];
  for (int kc = 0; kc < 98; kc++) {
    const u16x8 p = *reinterpret_cast<const u16x8*>(part + (size_t)kc * 262144 + r * 1024 + n8 * 8);
#pragma unroll
    for (int j = 0; j < 8; j++) s[j] += bf2f(p[j]);
  }
#pragma unroll
  for (int j = 0; j < 8; j++) h1[r * 1024 + n8 * 8 + j] = fmaxf(s[j], 0.f);
}

// h2 = relu(h1 @ W2 + b2): 4 rows per block
__global__ __launch_bounds__(256) void fcl2_k(const float* __restrict__ h1,
                                              const float* __restrict__ W2,
                                              const float* __restrict__ b2,
                                              float* __restrict__ h2) {
  const int r0 = blockIdx.x * 4;
  const int n = threadIdx.x;
  __shared__ float xr[4][1024];
  for (int i = threadIdx.x; i < 4096; i += 256) xr[i >> 10][i & 1023] = h1[r0 * 1024 + i];
  __syncthreads();
  float acc[4] = {b2[n], b2[n], b2[n], b2[n]};
  for (int k = 0; k < 1024; k++) {
    const float w = W2[k * 256 + n];
#pragma unroll
    for (int r = 0; r < 4; r++) acc[r] += xr[r][k] * w;
  }
#pragma unroll
  for (int r = 0; r < 4; r++) h2[(r0 + r) * 256 + n] = fmaxf(acc[r], 0.f);
}

__global__ void fcl3_k(const float* __restrict__ h2, const float* __restrict__ W3,
                       const float* __restrict__ b3, float* __restrict__ ms) {
  __shared__ float w[256];
  w[threadIdx.x] = W3[threadIdx.x];
  __syncthreads();
  const int r = threadIdx.x;
  float s = b3[0];
  for (int k = 0; k < 256; k++) s += h2[r * 256 + k] * w[k];
  ms[r] = 1.f / (1.f + expf(-s));
}

// trilinear upsample: (2,8,4,4) -> (2,16,224,224) f32 (this IS the mask output)
__global__ void upsample_k(const float* __restrict__ ms, float* __restrict__ mask) {
  const int idx = blockIdx.x * 256 + threadIdx.x;
  if (idx >= 2 * 16 * IHW * IHW) return;
  const int w = idx % IHW;
  const int h = (idx / IHW) % IHW;
  const int t = (idx / (IHW * IHW)) % 16;
  const int b = idx / (16 * IHW * IHW);

  const float tf = t * 0.5f - 0.25f;
  const float hf = (h + 0.5f) * (1.f / 56.f) - 0.5f;
  const float wf = (w + 0.5f) * (1.f / 56.f) - 0.5f;

  int t0 = (int)floorf(tf); const float ft = tf - t0;
  int h0 = (int)floorf(hf); const float fh = hf - h0;
  int w0 = (int)floorf(wf); const float fw = wf - w0;
  const int t1 = min(t0 + 1, 7); t0 = max(t0, 0);
  const int h1 = min(h0 + 1, 3); h0 = max(h0, 0);
  const int w1 = min(w0 + 1, 3); w0 = max(w0, 0);

  const float* p = ms + b * 128;
  auto at = [&](int tt, int hh, int ww) { return p[(tt * 4 + hh) * 4 + ww]; };
  const float c00 = at(t0, h0, w0) * (1.f - fw) + at(t0, h0, w1) * fw;
  const float c01 = at(t0, h1, w0) * (1.f - fw) + at(t0, h1, w1) * fw;
  const float c10 = at(t1, h0, w0) * (1.f - fw) + at(t1, h0, w1) * fw;
  const float c11 = at(t1, h1, w0) * (1.f - fw) + at(t1, h1, w1) * fw;
  const float c0 = c00 * (1.f - fh) + c01 * fh;
  const float c1 = c10 * (1.f - fh) + c11 * fh;
  mask[idx] = c0 * (1.f - ft) + c1 * ft;
}

// fused maxpool + spatial sum (bf16 in): one block per (head,b,oc,t) = 2048
__global__ __launch_bounds__(256) void pool_sum_k(const ushort* __restrict__ in,
                                                  float* __restrict__ psums) {
  const int blk = blockIdx.x;
  const ushort* p = in + (size_t)blk * (HO * HO);
  float s = 0.f;
  for (int idx = threadIdx.x; idx < PO * PO; idx += 256) {
    const int ho = idx / PO, wo = idx % PO;
    ushort m = 0;
    for (int dh = 0; dh < 3; dh++) {
      const int ih = 2 * ho + dh;
      if (ih >= HO) break;
      for (int dw = 0; dw < 3; dw++) {
        const int iw = 2 * wo + dw;
        if (iw >= HO) break;
        const ushort v = p[ih * HO + iw];
        m = (v > m) ? v : m;
      }
    }
    s += bf2f(m);
  }
  __shared__ float red[256];
  red[threadIdx.x] = s;
  __syncthreads();
  for (int off = 128; off > 0; off >>= 1) {
    if (threadIdx.x < off) red[threadIdx.x] += red[threadIdx.x + off];
    __syncthreads();
  }
  if (threadIdx.x == 0) psums[blk] = red[0];
}

// out[b_full*400 + l], b_full = head*2+b in [0,4)
__global__ void logits_k(const float* __restrict__ psums, const float* __restrict__ Wl,
                         const float* __restrict__ bl, float* __restrict__ out) {
  const int idx = blockIdx.x * 256 + threadIdx.x;
  if (idx >= 1600) return;
  const int bf = idx / 400, l = idx % 400;
  float s = bl[l];
  for (int oc = 0; oc < 64; oc++) {
    float ps = 0.f;
    for (int t = 0; t < 8; t++) ps += psums[(bf * 64 + oc) * 8 + t];
    s += (ps * (1.f / 25088.f)) * Wl[oc * 400 + l];
  }
  out[idx] = s;
}

extern "C" void kernel_launch(void* const* d_in, const int* in_sizes, int n_in,
                              void* d_out, int out_size, void* d_ws, size_t ws_size,
                              hipStream_t stream) {
  const float* rgbs   = (const float*)d_in[0];
  const float* flows  = (const float*)d_in[1];
  const float* bg     = (const float*)d_in[2];
  const float* w_rgb  = (const float*)d_in[3];
  const float* w_flow = (const float*)d_in[4];
  const float* w_feat = (const float*)d_in[5];
  const float* W1     = (const float*)d_in[6];
  const float* b1     = (const float*)d_in[7];
  const float* W2     = (const float*)d_in[8];
  const float* b2     = (const float*)d_in[9];
  const float* W3     = (const float*)d_in[10];
  const float* b3     = (const float*)d_in[11];
  const float* Wl     = (const float*)d_in[12];
  const float* bl     = (const float*)d_in[13];
  float* out = (float*)d_out;

  float* ws = (float*)d_ws;
  // A [0, 12845056)f: convbuf (bf16, up to z=4) / part (bf16, 98 chunks = exactly region A)
  ushort* convbuf = (ushort*)ws;
  ushort* part    = (ushort*)ws;                    // 25,690,112 ush
  // B [12845056, 16056320)f : X (6,422,528 ush)
  ushort* X       = (ushort*)(ws + 12845056);
  // C [16056320, ...)f : padded inputs; rgbsP(+flowsP contiguous) die after stems, maskedP aliases
  ushort* rgbsP   = (ushort*)(ws + 16056320);       // 10*21*232*240 = 11,692,800 ush contiguous
  ushort* flowsP  = (ushort*)(ws + 19564160);       // = rgbsP + 7,015,680
  ushort* maskedP = (ushort*)(ws + 16056320);       // 12*21*232*240 = 14,031,360 ush
  // tail
  float*  h1      = ws + 23100000;                  // 262,144
  float*  h2      = h1 + 262144;                    // 65,536
  float*  msmall  = h2 + 65536;                     // 256
  float*  psums   = msmall + 256;                   // 2048
  ushort* wrgb_b  = (ushort*)(psums + 2048);        // 71,680 ush (slot 86,016)
  ushort* wflow_b = wrgb_b + 86016;                 // 57,344 ush
  ushort* wfeat_b = wflow_b + 57344;                // 71,680 ush

  float* mask_full = out + 1600;

  // --- padded bf16 input prep + weight prep (fused launches) ---
  cvt_pad2<<<(5846400 + 255) / 256, 256, 0, stream>>>(rgbs, flows, rgbsP);
  wprep_all<<<(200704 + 255) / 256, 256, 0, stream>>>(w_rgb, w_flow, w_feat,
                                                      wrgb_b, wflow_b, wfeat_b);

  // --- mask branch stems ---
  conv_mfma<3><<<dim3(224, 8, 2), 256, 0, stream>>>(rgbsP, wrgb_b, convbuf);
  maxpool_gather<<<(1605632 + 255) / 256, 256, 0, stream>>>(convbuf, X, 0);
  conv_mfma<2><<<dim3(224, 8, 2), 256, 0, stream>>>(flowsP, wflow_b, convbuf);
  maxpool_gather<<<(1605632 + 255) / 256, 256, 0, stream>>>(convbuf, X, 12544);

  fcl1_mfma<<<dim3(8, 98), 512, 0, stream>>>(X, W1, part);
  h1_reduce<<<256, 128, 0, stream>>>(part, b1, h1);
  fcl2_k<<<64, 256, 0, stream>>>(h1, W2, b2, h2);
  fcl3_k<<<1, 256, 0, stream>>>(h2, W3, b3, msmall);
  upsample_k<<<(1605632 + 255) / 256, 256, 0, stream>>>(msmall, mask_full);

  // --- both feature heads merged; masking computes trilinear inline (no mask_full dep) ---
  masking_pad_f<<<(3507840 + 255) / 256, 256, 0, stream>>>(rgbs, msmall, bg, maskedP);
  conv_mfma<3><<<dim3(224, 8, 4), 256, 0, stream>>>(maskedP, wfeat_b, convbuf);
  pool_sum_k<<<2048, 256, 0, stream>>>(convbuf, psums);
  logits_k<<<7, 256, 0, stream>>>(psums, Wl, bl, out);
}